// Round 9
// baseline (1761.889 us; speedup 1.0000x reference)
//
#include <hip/hip_runtime.h>
#include <cstdint>
#include <cstddef>

#define NPOINT 512
#define NSAMPLE 32
#define NPB 8192  // points per batch

// Inputs: float32. Outputs: float32 flat concat (new_xyz, new_idx,
// new_features, sample_ids). Selection math (FPS argmax, ball d2<r2) must be
// bit-exact vs numpy f32: __f*_rn ops, no FMA contraction, exact tie-breaks.
__device__ __forceinline__ unsigned short f2bf(float f) {
  unsigned int u = __float_as_uint(f);
  unsigned int r = u + 0x7FFFu + ((u >> 16) & 1u);  // RNE
  return (unsigned short)(r >> 16);
}

// Wave64 f32 max via DPP (VALU-only, ~50 cy vs ~700 cy for 6x ds_bpermute
// shuffles — measured r4: shuffle-based reduce sat on the FPS critical path).
// Sequence: quad_perm[1,0,3,2], quad_perm[2,3,0,1], row_half_mirror,
// row_mirror, row_bcast15, row_bcast31 -> lane 63 holds the wave max;
// readlane(63) broadcasts it. With bound_ctrl=false and old=src, lanes with
// no valid DPP source keep their own value (fmax(x,x)=x), so full masks are
// safe. fmax of non-NaN values returns bitwise one of the inputs, so
// ballot(best==wmax) finds exact owners.
__device__ __forceinline__ float wave_max_f32(float x) {
  int xi = __float_as_int(x);
  int o;
  o = __builtin_amdgcn_update_dpp(xi, xi, 0xb1, 0xf, 0xf, false);   // quad_perm [1,0,3,2]
  x = fmaxf(x, __int_as_float(o)); xi = __float_as_int(x);
  o = __builtin_amdgcn_update_dpp(xi, xi, 0x4e, 0xf, 0xf, false);   // quad_perm [2,3,0,1]
  x = fmaxf(x, __int_as_float(o)); xi = __float_as_int(x);
  o = __builtin_amdgcn_update_dpp(xi, xi, 0x141, 0xf, 0xf, false);  // row_half_mirror
  x = fmaxf(x, __int_as_float(o)); xi = __float_as_int(x);
  o = __builtin_amdgcn_update_dpp(xi, xi, 0x140, 0xf, 0xf, false);  // row_mirror
  x = fmaxf(x, __int_as_float(o)); xi = __float_as_int(x);
  o = __builtin_amdgcn_update_dpp(xi, xi, 0x142, 0xf, 0xf, false);  // row_bcast15
  x = fmaxf(x, __int_as_float(o)); xi = __float_as_int(x);
  o = __builtin_amdgcn_update_dpp(xi, xi, 0x143, 0xf, 0xf, false);  // row_bcast31
  x = fmaxf(x, __int_as_float(o)); xi = __float_as_int(x);
  return __int_as_float(__builtin_amdgcn_readlane(xi, 63));
}

// ---------------------------------------------------------------- FPS
// One block (512 thr) per batch; thread t owns points [t*16, t*16+16) in
// registers (lane order == index order, so lowest tied lane == smallest
// index, matching jnp.argmax first-occurrence semantics). Per iteration:
// exact dist update + tree argmax (>= keeps smaller j); DPP wave max;
// owner lane (ballot+ffsll) publishes {d} and {x,y,z,idx} (one float4) to
// parity-buffered LDS; ONE barrier; every thread scans the 8 wave maxima
// (strict > keeps smallest wid) and reads the winner's float4.
// Reverted r1-r3 spatial-sort+skip: barrier makes per-iter time = slowest
// wave, and one wave always updates, so skip saved nothing and its 64-bit
// reduce cost +37%/iter (measured r4: 2.14 vs ~1.25 us/iter).
__global__ __launch_bounds__(512) void k_fps(const float* __restrict__ xyz,
                                             float* __restrict__ out_xyz,
                                             float* __restrict__ out_idx) {
  const int b = blockIdx.x;
  const int t = threadIdx.x;
  const float* xb = xyz + (size_t)b * NPB * 3;

  float px[16], py[16], pz[16], dist[16];
  {
    const float4* gp = reinterpret_cast<const float4*>(xb + (size_t)t * 48);
    float comp[48];
#pragma unroll
    for (int v = 0; v < 12; ++v) {
      float4 r = gp[v];
      comp[v * 4 + 0] = r.x;
      comp[v * 4 + 1] = r.y;
      comp[v * 4 + 2] = r.z;
      comp[v * 4 + 3] = r.w;
    }
#pragma unroll
    for (int j = 0; j < 16; ++j) {
      px[j] = comp[3 * j + 0];
      py[j] = comp[3 * j + 1];
      pz[j] = comp[3 * j + 2];
      dist[j] = 1e10f;
    }
  }

  __shared__ __align__(16) float sD[2][8];
  __shared__ __align__(16) float4 sV[2][8];  // {x, y, z, idx_as_float}

  const int wid = t >> 6;
  const int lane = t & 63;

  // selection 0 = index 0; q broadcast via (L2-hot) global read by all lanes
  float qx = xb[0], qy = xb[1], qz = xb[2];
  if (t == 0) {
    out_idx[b * NPOINT + 0] = 0.0f;
    size_t o = (size_t)(b * NPOINT) * 3;
    out_xyz[o + 0] = qx; out_xyz[o + 1] = qy; out_xyz[o + 2] = qz;
  }

  for (int it = 1; it < NPOINT; ++it) {
    // exact per-point update (same op order as reference; no FMA)
    float nd[16];
#pragma unroll
    for (int j = 0; j < 16; ++j) {
      float dx = __fsub_rn(px[j], qx);
      float dy = __fsub_rn(py[j], qy);
      float dz = __fsub_rn(pz[j], qz);
      float d2 = __fadd_rn(__fadd_rn(__fmul_rn(dx, dx), __fmul_rn(dy, dy)), __fmul_rn(dz, dz));
      float v = fminf(dist[j], d2);
      dist[j] = v;
      nd[j] = v;
    }
    // tree argmax over 16 (depth 4; ">=" keeps the smaller j == first max)
    int tj[16];
#pragma unroll
    for (int j = 0; j < 16; ++j) tj[j] = j;
#pragma unroll
    for (int st = 1; st < 16; st <<= 1) {
#pragma unroll
      for (int j = 0; j < 16; j += 2 * st) {
        bool a = nd[j] >= nd[j + st];
        nd[j] = a ? nd[j] : nd[j + st];
        tj[j] = a ? tj[j] : tj[j + st];
      }
    }
    const float best = nd[0];
    const int bi = tj[0];

    // wave-level f32 max (DPP; all lanes get wmax via readlane broadcast)
    const float wmax = wave_max_f32(best);
    const unsigned long long m = __ballot(best == wmax);
    const int p = it & 1;
    if (lane == (int)(__ffsll((unsigned long long)m) - 1)) {  // lowest tied lane
      sD[p][wid] = wmax;
      float sx_, sy_, sz_;
      switch (bi) {
        case 0:  sx_ = px[0];  sy_ = py[0];  sz_ = pz[0];  break;
        case 1:  sx_ = px[1];  sy_ = py[1];  sz_ = pz[1];  break;
        case 2:  sx_ = px[2];  sy_ = py[2];  sz_ = pz[2];  break;
        case 3:  sx_ = px[3];  sy_ = py[3];  sz_ = pz[3];  break;
        case 4:  sx_ = px[4];  sy_ = py[4];  sz_ = pz[4];  break;
        case 5:  sx_ = px[5];  sy_ = py[5];  sz_ = pz[5];  break;
        case 6:  sx_ = px[6];  sy_ = py[6];  sz_ = pz[6];  break;
        case 7:  sx_ = px[7];  sy_ = py[7];  sz_ = pz[7];  break;
        case 8:  sx_ = px[8];  sy_ = py[8];  sz_ = pz[8];  break;
        case 9:  sx_ = px[9];  sy_ = py[9];  sz_ = pz[9];  break;
        case 10: sx_ = px[10]; sy_ = py[10]; sz_ = pz[10]; break;
        case 11: sx_ = px[11]; sy_ = py[11]; sz_ = pz[11]; break;
        case 12: sx_ = px[12]; sy_ = py[12]; sz_ = pz[12]; break;
        case 13: sx_ = px[13]; sy_ = py[13]; sz_ = pz[13]; break;
        case 14: sx_ = px[14]; sy_ = py[14]; sz_ = pz[14]; break;
        default: sx_ = px[15]; sy_ = py[15]; sz_ = pz[15]; break;
      }
      sV[p][wid] = make_float4(sx_, sy_, sz_, (float)(t * 16 + bi));
    }
    __syncthreads();  // the only barrier per iteration
    // every thread scans the 8 wave winners (strict > => smallest wid on tie)
    const float4 d0 = *reinterpret_cast<const float4*>(&sD[p][0]);
    const float4 d1 = *reinterpret_cast<const float4*>(&sD[p][4]);
    float bd = d0.x;
    int bw = 0;
    if (d0.y > bd) { bd = d0.y; bw = 1; }
    if (d0.z > bd) { bd = d0.z; bw = 2; }
    if (d0.w > bd) { bd = d0.w; bw = 3; }
    if (d1.x > bd) { bd = d1.x; bw = 4; }
    if (d1.y > bd) { bd = d1.y; bw = 5; }
    if (d1.z > bd) { bd = d1.z; bw = 6; }
    if (d1.w > bd) { bd = d1.w; bw = 7; }
    const float4 wv = sV[p][bw];  // broadcast read (same addr all lanes)
    qx = wv.x; qy = wv.y; qz = wv.z;
    if (t == 0) {
      out_idx[b * NPOINT + it] = wv.w;
      size_t o = (size_t)(b * NPOINT + it) * 3;
      out_xyz[o + 0] = qx; out_xyz[o + 1] = qy; out_xyz[o + 2] = qz;
    }
  }
}

// ---------------------------------------------------------- feature transpose
// features f32 [64][Ntot] -> feat_t bf16 [Ntot][64]
__global__ __launch_bounds__(256) void k_transpose(const float* __restrict__ in,
                                                   unsigned short* __restrict__ out,
                                                   int Ntot) {
  __shared__ __align__(16) unsigned short tile[64][65];
  const int t = threadIdx.x;
  const int n0 = blockIdx.x * 64;
#pragma unroll
  for (int i = 0; i < 16; ++i) {
    int c = i * 4 + (t >> 6);
    int n = t & 63;
    tile[c][n] = f2bf(in[(size_t)c * Ntot + n0 + n]);
  }
  __syncthreads();
#pragma unroll
  for (int i = 0; i < 16; ++i) {
    int n = i * 4 + (t >> 6);
    int c = t & 63;
    out[(size_t)(n0 + n) * 64 + c] = tile[c][n];
  }
}

// ---------------------------------------------------------------- ball query
// One wave per center (8 waves/block). Fixed 64 rounds x 2 points/lane: no
// data-dependent loop condition, so loads pipeline across rounds. Ordered
// compaction via ballot+popcount (first-64 sub-block before second-64 keeps
// index order). Exact f32 math, strict <.
__global__ __launch_bounds__(512) void k_ball(const float* __restrict__ xyz,
                                              const float* __restrict__ fps_idx_f,
                                              float* __restrict__ sids_f) {
  __shared__ int slots[8 * NSAMPLE];
  const int b = blockIdx.x >> 6;
  const int cbase = (blockIdx.x & 63) * 8;
  const int t = threadIdx.x;
  const float* xb = xyz + (size_t)b * NPB * 3;

  const int w = t >> 6, lane = t & 63;
  const int c_local = cbase + w;
  const int ci = (int)fps_idx_f[b * NPOINT + c_local];
  const float cx = xb[ci * 3 + 0];
  const float cy = xb[ci * 3 + 1];
  const float cz = xb[ci * 3 + 2];
  const float R2 = 0.01f;  // f32(0.1*0.1), numpy weak-scalar promotion
  const unsigned long long below = (1ull << lane) - 1ull;

  int cnt = 0;
#pragma unroll 4
  for (int r = 0; r < 64; ++r) {
    const int p0 = r * 128 + lane;
    const int p1 = p0 + 64;
    float ax = xb[p0 * 3 + 0], ay = xb[p0 * 3 + 1], az = xb[p0 * 3 + 2];
    float bx = xb[p1 * 3 + 0], by = xb[p1 * 3 + 1], bz = xb[p1 * 3 + 2];
    float dxa = __fsub_rn(ax, cx), dya = __fsub_rn(ay, cy), dza = __fsub_rn(az, cz);
    float dxb = __fsub_rn(bx, cx), dyb = __fsub_rn(by, cy), dzb = __fsub_rn(bz, cz);
    float d2a = __fadd_rn(__fadd_rn(__fmul_rn(dxa, dxa), __fmul_rn(dya, dya)), __fmul_rn(dza, dza));
    float d2b = __fadd_rn(__fadd_rn(__fmul_rn(dxb, dxb), __fmul_rn(dyb, dyb)), __fmul_rn(dzb, dzb));
    const bool i0 = d2a < R2;
    const bool i1 = d2b < R2;
    const unsigned long long m0 = __ballot(i0);
    if (i0) {
      int pos = cnt + (int)__popcll(m0 & below);
      if (pos < NSAMPLE) slots[w * NSAMPLE + pos] = p0;
    }
    cnt += (int)__popcll(m0);
    const unsigned long long m1 = __ballot(i1);
    if (i1) {
      int pos = cnt + (int)__popcll(m1 & below);
      if (pos < NSAMPLE) slots[w * NSAMPLE + pos] = p1;
    }
    cnt += (int)__popcll(m1);
  }
  if (lane < NSAMPLE) {
    const int first = (cnt > 0) ? slots[w * NSAMPLE] : 0;
    const int v = (lane < cnt) ? slots[w * NSAMPLE + lane] : first;
    sids_f[((size_t)(b * NPOINT + c_local)) * NSAMPLE + lane] = (float)v;
  }
}

// ------------------------------------------------------- gather + MLP + max
// 32 lanes = 32 samples, 2 centers per wave, 8 centers per 256-thr block.
// W0/W2 f32 in LDS, W1 bf16 in LDS (~59 KB). h1/h2 in registers.
__global__ __launch_bounds__(256) void k_mlp(const float* __restrict__ xyz,
                                             const float* __restrict__ feat,
                                             const unsigned short* __restrict__ feat_t,
                                             const float* __restrict__ fps_idx_f,
                                             const float* __restrict__ sids_f,
                                             const float* __restrict__ w0g,
                                             const float* __restrict__ b0g,
                                             const float* __restrict__ w1g,
                                             const float* __restrict__ b1g,
                                             const float* __restrict__ w2g,
                                             const float* __restrict__ b2g,
                                             float* __restrict__ out_feat,
                                             int Ntot, int useT) {
  __shared__ __align__(16) float W0s[64 * 68];            // padded rows (c 67 = 0)
  __shared__ __align__(16) unsigned short W1s[64 * 64];   // bf16
  __shared__ __align__(16) float W2s[128 * 64];
  __shared__ float b0s[64], b1s[64], b2s[128];
  const int t = threadIdx.x;
  for (int i = t; i < 64 * 68; i += 256) {
    int r = i / 68, c = i - r * 68;
    W0s[i] = (c < 67) ? w0g[r * 67 + c] : 0.0f;
  }
  for (int i = t; i < 64 * 64; i += 256) W1s[i] = f2bf(w1g[i]);
  for (int i = t; i < 128 * 64; i += 256) W2s[i] = w2g[i];
  if (t < 64) b0s[t] = b0g[t];
  if (t < 64) b1s[t] = b1g[t];
  if (t < 128) b2s[t] = b2g[t];
  __syncthreads();

  const int b = blockIdx.x >> 6;
  const int c_local = (blockIdx.x & 63) * 8 + (t >> 5);
  const int s = t & 31;
  const int ci = (int)fps_idx_f[b * NPOINT + c_local];
  const float cx = xyz[((size_t)b * NPB + ci) * 3 + 0];
  const float cy = xyz[((size_t)b * NPB + ci) * 3 + 1];
  const float cz = xyz[((size_t)b * NPB + ci) * 3 + 2];
  const int id = (int)sids_f[((size_t)(b * NPOINT + c_local)) * NSAMPLE + s];

  float g[68];
  {
    const size_t pb = ((size_t)b * NPB + id) * 3;
    g[0] = __fsub_rn(xyz[pb + 0], cx);
    g[1] = __fsub_rn(xyz[pb + 1], cy);
    g[2] = __fsub_rn(xyz[pb + 2], cz);
    if (useT) {
      const uint4* fp = reinterpret_cast<const uint4*>(feat_t + ((size_t)b * NPB + id) * 64);
#pragma unroll
      for (int v = 0; v < 8; ++v) {
        uint4 r = fp[v];
        unsigned int vs[4] = {r.x, r.y, r.z, r.w};
#pragma unroll
        for (int q = 0; q < 4; ++q) {
          g[3 + v * 8 + q * 2 + 0] = __uint_as_float(vs[q] << 16);
          g[3 + v * 8 + q * 2 + 1] = __uint_as_float(vs[q] & 0xFFFF0000u);
        }
      }
    } else {
      const float* col = feat + (size_t)(b * NPB + id);
#pragma unroll 8
      for (int c = 0; c < 64; ++c) g[3 + c] = col[(size_t)c * Ntot];
    }
    g[67] = 0.0f;
  }

  float h1[64];
#pragma unroll
  for (int o = 0; o < 64; ++o) {
    float acc = b0s[o];
    const float4* wp = reinterpret_cast<const float4*>(&W0s[o * 68]);
#pragma unroll
    for (int c4 = 0; c4 < 17; ++c4) {
      float4 wv = wp[c4];
      acc += wv.x * g[c4 * 4 + 0];
      acc += wv.y * g[c4 * 4 + 1];
      acc += wv.z * g[c4 * 4 + 2];
      acc += wv.w * g[c4 * 4 + 3];
    }
    h1[o] = fmaxf(acc, 0.0f);
  }
  float h2[64];
#pragma unroll
  for (int o = 0; o < 64; ++o) {
    float acc = b1s[o];
    const uint2* wp = reinterpret_cast<const uint2*>(&W1s[o * 64]);
#pragma unroll
    for (int c4 = 0; c4 < 16; ++c4) {
      uint2 u = wp[c4];
      acc += __uint_as_float(u.x << 16) * h1[c4 * 4 + 0];
      acc += __uint_as_float(u.x & 0xFFFF0000u) * h1[c4 * 4 + 1];
      acc += __uint_as_float(u.y << 16) * h1[c4 * 4 + 2];
      acc += __uint_as_float(u.y & 0xFFFF0000u) * h1[c4 * 4 + 3];
    }
    h2[o] = fmaxf(acc, 0.0f);
  }
#pragma unroll 1
  for (int o = 0; o < 128; ++o) {
    float acc = b2s[o];
    const float4* wp = reinterpret_cast<const float4*>(&W2s[o * 64]);
#pragma unroll
    for (int c4 = 0; c4 < 16; ++c4) {
      float4 wv = wp[c4];
      acc += wv.x * h2[c4 * 4 + 0];
      acc += wv.y * h2[c4 * 4 + 1];
      acc += wv.z * h2[c4 * 4 + 2];
      acc += wv.w * h2[c4 * 4 + 3];
    }
    float v = fmaxf(acc, 0.0f);
#pragma unroll
    for (int off = 16; off >= 1; off >>= 1) v = fmaxf(v, __shfl_xor(v, off));
    if (s == 0) out_feat[((size_t)b * 128 + o) * NPOINT + c_local] = v;
  }
}

// ------------------------------------------------------------------- launch
extern "C" void kernel_launch(void* const* d_in, const int* in_sizes, int n_in,
                              void* d_out, int out_size, void* d_ws, size_t ws_size,
                              hipStream_t stream) {
  (void)n_in; (void)out_size;
  const float* xyz = (const float*)d_in[0];
  const float* feat = (const float*)d_in[1];
  // d_in[2] = num_points (8192, fixed by setup)
  const float* w0 = (const float*)d_in[3];
  const float* b0 = (const float*)d_in[4];
  const float* w1 = (const float*)d_in[5];
  const float* b1 = (const float*)d_in[6];
  const float* w2 = (const float*)d_in[7];
  const float* b2 = (const float*)d_in[8];

  const int Ntot = in_sizes[0] / 3;   // 65536
  const int B = Ntot / NPB;           // 8

  float* out = (float*)d_out;
  float* o_xyz = out;                                    // [B,512,3]
  float* o_idx = o_xyz + (size_t)B * NPOINT * 3;         // [B,512]
  float* o_feat = o_idx + (size_t)B * NPOINT;            // [B,128,512]
  float* o_sids = o_feat + (size_t)B * 128 * NPOINT;     // [B,512,32]

  // Workspace: only the transposed-features buffer (bf16), only if it fits.
  const size_t ft_bytes = (size_t)Ntot * 64 * 2;         // 8 MB
  const int useT = (ws_size >= ft_bytes) ? 1 : 0;
  unsigned short* ft_ws = (unsigned short*)d_ws;

  if (useT) {
    k_transpose<<<dim3(Ntot / 64), dim3(256), 0, stream>>>(feat, ft_ws, Ntot);
  }
  k_fps<<<dim3(B), dim3(512), 0, stream>>>(xyz, o_xyz, o_idx);
  k_ball<<<dim3(B * 64), dim3(512), 0, stream>>>(xyz, o_idx, o_sids);
  k_mlp<<<dim3(B * 64), dim3(256), 0, stream>>>(xyz, feat, ft_ws, o_idx, o_sids,
                                                w0, b0, w1, b1, w2, b2, o_feat,
                                                Ntot, useT);
}

// Round 12
// 883.916 us; speedup vs baseline: 1.9933x; 1.9933x over previous
//
#include <hip/hip_runtime.h>
#include <cstdint>
#include <cstddef>

#define NPOINT 512
#define NSAMPLE 32
#define NPB 8192  // points per batch

// Inputs: float32. Outputs: float32 flat concat (new_xyz, new_idx,
// new_features, sample_ids). Selection math (FPS argmax, ball d2<r2) must be
// bit-exact vs numpy f32: __f*_rn ops, no FMA contraction, exact tie-breaks.
__device__ __forceinline__ unsigned short f2bf(float f) {
  unsigned int u = __float_as_uint(f);
  unsigned int r = u + 0x7FFFu + ((u >> 16) & 1u);  // RNE
  return (unsigned short)(r >> 16);
}

// Wave64 f32 max via DPP (VALU-only). Canonical rocPRIM sequence; lane 63
// ends with the full wave max, readlane(63) broadcasts. bound_ctrl=false
// with old=src => sourceless lanes compute fmax(x,x)=x (harmless).
// r9 verified this path: bank conflicts 0, LDS 512B. The r9 slowdown was
// NOT the DPP — it was tree-argmax register blowup (VGPR 72->56 forced
// per-iteration spill/reload of the point arrays).
__device__ __forceinline__ float wave_max_f32(float x) {
  int xi = __float_as_int(x);
  int o;
  o = __builtin_amdgcn_update_dpp(xi, xi, 0xb1, 0xf, 0xf, false);   // quad_perm [1,0,3,2]
  x = fmaxf(x, __int_as_float(o)); xi = __float_as_int(x);
  o = __builtin_amdgcn_update_dpp(xi, xi, 0x4e, 0xf, 0xf, false);   // quad_perm [2,3,0,1]
  x = fmaxf(x, __int_as_float(o)); xi = __float_as_int(x);
  o = __builtin_amdgcn_update_dpp(xi, xi, 0x141, 0xf, 0xf, false);  // row_half_mirror
  x = fmaxf(x, __int_as_float(o)); xi = __float_as_int(x);
  o = __builtin_amdgcn_update_dpp(xi, xi, 0x140, 0xf, 0xf, false);  // row_mirror
  x = fmaxf(x, __int_as_float(o)); xi = __float_as_int(x);
  o = __builtin_amdgcn_update_dpp(xi, xi, 0x142, 0xf, 0xf, false);  // row_bcast15
  x = fmaxf(x, __int_as_float(o)); xi = __float_as_int(x);
  o = __builtin_amdgcn_update_dpp(xi, xi, 0x143, 0xf, 0xf, false);  // row_bcast31
  x = fmaxf(x, __int_as_float(o)); xi = __float_as_int(x);
  return __int_as_float(__builtin_amdgcn_readlane(xi, 63));
}

// ---------------------------------------------------------------- FPS
// One block (1024 thr = 16 waves) per batch; thread t owns points
// [t*8, t*8+8) in registers (lane order == index order, so lowest tied
// lane == smallest index == jnp.argmax first-occurrence). Per iteration:
// exact dist update with SERIAL argmax fused in (best/bi scalars only —
// low register pressure, the r9 lesson); DPP wave max; owner lane
// (ballot+ffsll) publishes wmax + {x,y,z,idx} float4 to parity-buffered
// LDS; ONE barrier; every thread scans the 16 wave maxima (strict > keeps
// smallest wid) and reads the winner's float4.
// Block=1024 (vs 512x16pts): halves per-wave VALU issue in the distance
// update, the dominant critical-path segment at 8 blocks / 256 CUs.
__global__ __launch_bounds__(1024) void k_fps(const float* __restrict__ xyz,
                                              float* __restrict__ out_xyz,
                                              float* __restrict__ out_idx) {
  const int b = blockIdx.x;
  const int t = threadIdx.x;
  const float* xb = xyz + (size_t)b * NPB * 3;

  float px[8], py[8], pz[8], dist[8];
  {
    const float4* gp = reinterpret_cast<const float4*>(xb + (size_t)t * 24);
    float comp[24];
#pragma unroll
    for (int v = 0; v < 6; ++v) {
      float4 r = gp[v];
      comp[v * 4 + 0] = r.x;
      comp[v * 4 + 1] = r.y;
      comp[v * 4 + 2] = r.z;
      comp[v * 4 + 3] = r.w;
    }
#pragma unroll
    for (int j = 0; j < 8; ++j) {
      px[j] = comp[3 * j + 0];
      py[j] = comp[3 * j + 1];
      pz[j] = comp[3 * j + 2];
      dist[j] = 1e10f;
    }
  }

  __shared__ __align__(16) float sD[2][16];
  __shared__ __align__(16) float4 sV[2][16];  // {x, y, z, idx_as_float}

  const int wid = t >> 6;
  const int lane = t & 63;

  // selection 0 = index 0; q broadcast via (L2-hot) global read by all lanes
  float qx = xb[0], qy = xb[1], qz = xb[2];
  if (t == 0) {
    out_idx[b * NPOINT + 0] = 0.0f;
    size_t o = (size_t)(b * NPOINT) * 3;
    out_xyz[o + 0] = qx; out_xyz[o + 1] = qy; out_xyz[o + 2] = qz;
  }

  for (int it = 1; it < NPOINT; ++it) {
    // exact per-point update + serial argmax (strict > keeps smallest j)
    float best = -1.0f;
    int bi = 0;
#pragma unroll
    for (int j = 0; j < 8; ++j) {
      float dx = __fsub_rn(px[j], qx);
      float dy = __fsub_rn(py[j], qy);
      float dz = __fsub_rn(pz[j], qz);
      float d2 = __fadd_rn(__fadd_rn(__fmul_rn(dx, dx), __fmul_rn(dy, dy)), __fmul_rn(dz, dz));
      float nd = fminf(dist[j], d2);
      dist[j] = nd;
      if (nd > best) { best = nd; bi = j; }
    }

    // wave-level f32 max (DPP; all lanes get wmax via readlane broadcast)
    const float wmax = wave_max_f32(best);
    const unsigned long long m = __ballot(best == wmax);
    const int p = it & 1;
    if (lane == (int)(__ffsll((unsigned long long)m) - 1)) {  // lowest tied lane
      sD[p][wid] = wmax;
      float sx_, sy_, sz_;
      switch (bi) {
        case 0:  sx_ = px[0]; sy_ = py[0]; sz_ = pz[0]; break;
        case 1:  sx_ = px[1]; sy_ = py[1]; sz_ = pz[1]; break;
        case 2:  sx_ = px[2]; sy_ = py[2]; sz_ = pz[2]; break;
        case 3:  sx_ = px[3]; sy_ = py[3]; sz_ = pz[3]; break;
        case 4:  sx_ = px[4]; sy_ = py[4]; sz_ = pz[4]; break;
        case 5:  sx_ = px[5]; sy_ = py[5]; sz_ = pz[5]; break;
        case 6:  sx_ = px[6]; sy_ = py[6]; sz_ = pz[6]; break;
        default: sx_ = px[7]; sy_ = py[7]; sz_ = pz[7]; break;
      }
      sV[p][wid] = make_float4(sx_, sy_, sz_, (float)(t * 8 + bi));
    }
    __syncthreads();  // the only barrier per iteration
    // every thread scans the 16 wave winners (strict > => smallest wid on tie)
    const float4 d0 = *reinterpret_cast<const float4*>(&sD[p][0]);
    const float4 d1 = *reinterpret_cast<const float4*>(&sD[p][4]);
    const float4 d2 = *reinterpret_cast<const float4*>(&sD[p][8]);
    const float4 d3 = *reinterpret_cast<const float4*>(&sD[p][12]);
    float bd = d0.x;
    int bw = 0;
    if (d0.y > bd) { bd = d0.y; bw = 1; }
    if (d0.z > bd) { bd = d0.z; bw = 2; }
    if (d0.w > bd) { bd = d0.w; bw = 3; }
    if (d1.x > bd) { bd = d1.x; bw = 4; }
    if (d1.y > bd) { bd = d1.y; bw = 5; }
    if (d1.z > bd) { bd = d1.z; bw = 6; }
    if (d1.w > bd) { bd = d1.w; bw = 7; }
    if (d2.x > bd) { bd = d2.x; bw = 8; }
    if (d2.y > bd) { bd = d2.y; bw = 9; }
    if (d2.z > bd) { bd = d2.z; bw = 10; }
    if (d2.w > bd) { bd = d2.w; bw = 11; }
    if (d3.x > bd) { bd = d3.x; bw = 12; }
    if (d3.y > bd) { bd = d3.y; bw = 13; }
    if (d3.z > bd) { bd = d3.z; bw = 14; }
    if (d3.w > bd) { bd = d3.w; bw = 15; }
    const float4 wv = sV[p][bw];  // broadcast read (same addr all lanes)
    qx = wv.x; qy = wv.y; qz = wv.z;
    if (t == 0) {
      out_idx[b * NPOINT + it] = wv.w;
      size_t o = (size_t)(b * NPOINT + it) * 3;
      out_xyz[o + 0] = qx; out_xyz[o + 1] = qy; out_xyz[o + 2] = qz;
    }
  }
}

// ---------------------------------------------------------- feature transpose
// features f32 [64][Ntot] -> feat_t bf16 [Ntot][64]
__global__ __launch_bounds__(256) void k_transpose(const float* __restrict__ in,
                                                   unsigned short* __restrict__ out,
                                                   int Ntot) {
  __shared__ __align__(16) unsigned short tile[64][65];
  const int t = threadIdx.x;
  const int n0 = blockIdx.x * 64;
#pragma unroll
  for (int i = 0; i < 16; ++i) {
    int c = i * 4 + (t >> 6);
    int n = t & 63;
    tile[c][n] = f2bf(in[(size_t)c * Ntot + n0 + n]);
  }
  __syncthreads();
#pragma unroll
  for (int i = 0; i < 16; ++i) {
    int n = i * 4 + (t >> 6);
    int c = t & 63;
    out[(size_t)(n0 + n) * 64 + c] = tile[c][n];
  }
}

// ---------------------------------------------------------------- ball query
// One wave per center (8 waves/block). Fixed 64 rounds x 2 points/lane: no
// data-dependent loop condition, so loads pipeline across rounds. Ordered
// compaction via ballot+popcount (first-64 sub-block before second-64 keeps
// index order). Exact f32 math, strict <.
__global__ __launch_bounds__(512) void k_ball(const float* __restrict__ xyz,
                                              const float* __restrict__ fps_idx_f,
                                              float* __restrict__ sids_f) {
  __shared__ int slots[8 * NSAMPLE];
  const int b = blockIdx.x >> 6;
  const int cbase = (blockIdx.x & 63) * 8;
  const int t = threadIdx.x;
  const float* xb = xyz + (size_t)b * NPB * 3;

  const int w = t >> 6, lane = t & 63;
  const int c_local = cbase + w;
  const int ci = (int)fps_idx_f[b * NPOINT + c_local];
  const float cx = xb[ci * 3 + 0];
  const float cy = xb[ci * 3 + 1];
  const float cz = xb[ci * 3 + 2];
  const float R2 = 0.01f;  // f32(0.1*0.1), numpy weak-scalar promotion
  const unsigned long long below = (1ull << lane) - 1ull;

  int cnt = 0;
#pragma unroll 4
  for (int r = 0; r < 64; ++r) {
    const int p0 = r * 128 + lane;
    const int p1 = p0 + 64;
    float ax = xb[p0 * 3 + 0], ay = xb[p0 * 3 + 1], az = xb[p0 * 3 + 2];
    float bx = xb[p1 * 3 + 0], by = xb[p1 * 3 + 1], bz = xb[p1 * 3 + 2];
    float dxa = __fsub_rn(ax, cx), dya = __fsub_rn(ay, cy), dza = __fsub_rn(az, cz);
    float dxb = __fsub_rn(bx, cx), dyb = __fsub_rn(by, cy), dzb = __fsub_rn(bz, cz);
    float d2a = __fadd_rn(__fadd_rn(__fmul_rn(dxa, dxa), __fmul_rn(dya, dya)), __fmul_rn(dza, dza));
    float d2b = __fadd_rn(__fadd_rn(__fmul_rn(dxb, dxb), __fmul_rn(dyb, dyb)), __fmul_rn(dzb, dzb));
    const bool i0 = d2a < R2;
    const bool i1 = d2b < R2;
    const unsigned long long m0 = __ballot(i0);
    if (i0) {
      int pos = cnt + (int)__popcll(m0 & below);
      if (pos < NSAMPLE) slots[w * NSAMPLE + pos] = p0;
    }
    cnt += (int)__popcll(m0);
    const unsigned long long m1 = __ballot(i1);
    if (i1) {
      int pos = cnt + (int)__popcll(m1 & below);
      if (pos < NSAMPLE) slots[w * NSAMPLE + pos] = p1;
    }
    cnt += (int)__popcll(m1);
  }
  if (lane < NSAMPLE) {
    const int first = (cnt > 0) ? slots[w * NSAMPLE] : 0;
    const int v = (lane < cnt) ? slots[w * NSAMPLE + lane] : first;
    sids_f[((size_t)(b * NPOINT + c_local)) * NSAMPLE + lane] = (float)v;
  }
}

// ------------------------------------------------------- gather + MLP + max
// 32 lanes = 32 samples, 2 centers per wave, 8 centers per 256-thr block.
// W0/W2 f32 in LDS, W1 bf16 in LDS (~59 KB). h1/h2 in registers.
__global__ __launch_bounds__(256) void k_mlp(const float* __restrict__ xyz,
                                             const float* __restrict__ feat,
                                             const unsigned short* __restrict__ feat_t,
                                             const float* __restrict__ fps_idx_f,
                                             const float* __restrict__ sids_f,
                                             const float* __restrict__ w0g,
                                             const float* __restrict__ b0g,
                                             const float* __restrict__ w1g,
                                             const float* __restrict__ b1g,
                                             const float* __restrict__ w2g,
                                             const float* __restrict__ b2g,
                                             float* __restrict__ out_feat,
                                             int Ntot, int useT) {
  __shared__ __align__(16) float W0s[64 * 68];            // padded rows (c 67 = 0)
  __shared__ __align__(16) unsigned short W1s[64 * 64];   // bf16
  __shared__ __align__(16) float W2s[128 * 64];
  __shared__ float b0s[64], b1s[64], b2s[128];
  const int t = threadIdx.x;
  for (int i = t; i < 64 * 68; i += 256) {
    int r = i / 68, c = i - r * 68;
    W0s[i] = (c < 67) ? w0g[r * 67 + c] : 0.0f;
  }
  for (int i = t; i < 64 * 64; i += 256) W1s[i] = f2bf(w1g[i]);
  for (int i = t; i < 128 * 64; i += 256) W2s[i] = w2g[i];
  if (t < 64) b0s[t] = b0g[t];
  if (t < 64) b1s[t] = b1g[t];
  if (t < 128) b2s[t] = b2g[t];
  __syncthreads();

  const int b = blockIdx.x >> 6;
  const int c_local = (blockIdx.x & 63) * 8 + (t >> 5);
  const int s = t & 31;
  const int ci = (int)fps_idx_f[b * NPOINT + c_local];
  const float cx = xyz[((size_t)b * NPB + ci) * 3 + 0];
  const float cy = xyz[((size_t)b * NPB + ci) * 3 + 1];
  const float cz = xyz[((size_t)b * NPB + ci) * 3 + 2];
  const int id = (int)sids_f[((size_t)(b * NPOINT + c_local)) * NSAMPLE + s];

  float g[68];
  {
    const size_t pb = ((size_t)b * NPB + id) * 3;
    g[0] = __fsub_rn(xyz[pb + 0], cx);
    g[1] = __fsub_rn(xyz[pb + 1], cy);
    g[2] = __fsub_rn(xyz[pb + 2], cz);
    if (useT) {
      const uint4* fp = reinterpret_cast<const uint4*>(feat_t + ((size_t)b * NPB + id) * 64);
#pragma unroll
      for (int v = 0; v < 8; ++v) {
        uint4 r = fp[v];
        unsigned int vs[4] = {r.x, r.y, r.z, r.w};
#pragma unroll
        for (int q = 0; q < 4; ++q) {
          g[3 + v * 8 + q * 2 + 0] = __uint_as_float(vs[q] << 16);
          g[3 + v * 8 + q * 2 + 1] = __uint_as_float(vs[q] & 0xFFFF0000u);
        }
      }
    } else {
      const float* col = feat + (size_t)(b * NPB + id);
#pragma unroll 8
      for (int c = 0; c < 64; ++c) g[3 + c] = col[(size_t)c * Ntot];
    }
    g[67] = 0.0f;
  }

  float h1[64];
#pragma unroll
  for (int o = 0; o < 64; ++o) {
    float acc = b0s[o];
    const float4* wp = reinterpret_cast<const float4*>(&W0s[o * 68]);
#pragma unroll
    for (int c4 = 0; c4 < 17; ++c4) {
      float4 wv = wp[c4];
      acc += wv.x * g[c4 * 4 + 0];
      acc += wv.y * g[c4 * 4 + 1];
      acc += wv.z * g[c4 * 4 + 2];
      acc += wv.w * g[c4 * 4 + 3];
    }
    h1[o] = fmaxf(acc, 0.0f);
  }
  float h2[64];
#pragma unroll
  for (int o = 0; o < 64; ++o) {
    float acc = b1s[o];
    const uint2* wp = reinterpret_cast<const uint2*>(&W1s[o * 64]);
#pragma unroll
    for (int c4 = 0; c4 < 16; ++c4) {
      uint2 u = wp[c4];
      acc += __uint_as_float(u.x << 16) * h1[c4 * 4 + 0];
      acc += __uint_as_float(u.x & 0xFFFF0000u) * h1[c4 * 4 + 1];
      acc += __uint_as_float(u.y << 16) * h1[c4 * 4 + 2];
      acc += __uint_as_float(u.y & 0xFFFF0000u) * h1[c4 * 4 + 3];
    }
    h2[o] = fmaxf(acc, 0.0f);
  }
#pragma unroll 1
  for (int o = 0; o < 128; ++o) {
    float acc = b2s[o];
    const float4* wp = reinterpret_cast<const float4*>(&W2s[o * 64]);
#pragma unroll
    for (int c4 = 0; c4 < 16; ++c4) {
      float4 wv = wp[c4];
      acc += wv.x * h2[c4 * 4 + 0];
      acc += wv.y * h2[c4 * 4 + 1];
      acc += wv.z * h2[c4 * 4 + 2];
      acc += wv.w * h2[c4 * 4 + 3];
    }
    float v = fmaxf(acc, 0.0f);
#pragma unroll
    for (int off = 16; off >= 1; off >>= 1) v = fmaxf(v, __shfl_xor(v, off));
    if (s == 0) out_feat[((size_t)b * 128 + o) * NPOINT + c_local] = v;
  }
}

// ------------------------------------------------------------------- launch
extern "C" void kernel_launch(void* const* d_in, const int* in_sizes, int n_in,
                              void* d_out, int out_size, void* d_ws, size_t ws_size,
                              hipStream_t stream) {
  (void)n_in; (void)out_size;
  const float* xyz = (const float*)d_in[0];
  const float* feat = (const float*)d_in[1];
  // d_in[2] = num_points (8192, fixed by setup)
  const float* w0 = (const float*)d_in[3];
  const float* b0 = (const float*)d_in[4];
  const float* w1 = (const float*)d_in[5];
  const float* b1 = (const float*)d_in[6];
  const float* w2 = (const float*)d_in[7];
  const float* b2 = (const float*)d_in[8];

  const int Ntot = in_sizes[0] / 3;   // 65536
  const int B = Ntot / NPB;           // 8

  float* out = (float*)d_out;
  float* o_xyz = out;                                    // [B,512,3]
  float* o_idx = o_xyz + (size_t)B * NPOINT * 3;         // [B,512]
  float* o_feat = o_idx + (size_t)B * NPOINT;            // [B,128,512]
  float* o_sids = o_feat + (size_t)B * 128 * NPOINT;     // [B,512,32]

  // Workspace: only the transposed-features buffer (bf16), only if it fits.
  const size_t ft_bytes = (size_t)Ntot * 64 * 2;         // 8 MB
  const int useT = (ws_size >= ft_bytes) ? 1 : 0;
  unsigned short* ft_ws = (unsigned short*)d_ws;

  if (useT) {
    k_transpose<<<dim3(Ntot / 64), dim3(256), 0, stream>>>(feat, ft_ws, Ntot);
  }
  k_fps<<<dim3(B), dim3(1024), 0, stream>>>(xyz, o_xyz, o_idx);
  k_ball<<<dim3(B * 64), dim3(512), 0, stream>>>(xyz, o_idx, o_sids);
  k_mlp<<<dim3(B * 64), dim3(256), 0, stream>>>(xyz, feat, ft_ws, o_idx, o_sids,
                                                w0, b0, w1, b1, w2, b2, o_feat,
                                                Ntot, useT);
}

// Round 13
// 879.711 us; speedup vs baseline: 2.0028x; 1.0048x over previous
//
#include <hip/hip_runtime.h>
#include <cstdint>
#include <cstddef>

#define NPOINT 512
#define NSAMPLE 32
#define NPB 8192  // points per batch

// Inputs: float32. Outputs: float32 flat concat (new_xyz, new_idx,
// new_features, sample_ids). Selection math (FPS argmax, ball d2<r2) must be
// bit-exact vs numpy f32: __f*_rn ops, no FMA contraction, exact tie-breaks.
__device__ __forceinline__ unsigned short f2bf(float f) {
  unsigned int u = __float_as_uint(f);
  unsigned int r = u + 0x7FFFu + ((u >> 16) & 1u);  // RNE
  return (unsigned short)(r >> 16);
}

// Wave64 f32 max via DPP (VALU-only). Canonical rocPRIM sequence; lane 63
// ends with the full wave max, readlane(63) broadcasts. bound_ctrl=false
// with old=src => sourceless lanes compute fmax(x,x)=x (harmless).
// r9/r12 verified: bank conflicts 0, tiny LDS.
__device__ __forceinline__ float wave_max_f32(float x) {
  int xi = __float_as_int(x);
  int o;
  o = __builtin_amdgcn_update_dpp(xi, xi, 0xb1, 0xf, 0xf, false);   // quad_perm [1,0,3,2]
  x = fmaxf(x, __int_as_float(o)); xi = __float_as_int(x);
  o = __builtin_amdgcn_update_dpp(xi, xi, 0x4e, 0xf, 0xf, false);   // quad_perm [2,3,0,1]
  x = fmaxf(x, __int_as_float(o)); xi = __float_as_int(x);
  o = __builtin_amdgcn_update_dpp(xi, xi, 0x141, 0xf, 0xf, false);  // row_half_mirror
  x = fmaxf(x, __int_as_float(o)); xi = __float_as_int(x);
  o = __builtin_amdgcn_update_dpp(xi, xi, 0x140, 0xf, 0xf, false);  // row_mirror
  x = fmaxf(x, __int_as_float(o)); xi = __float_as_int(x);
  o = __builtin_amdgcn_update_dpp(xi, xi, 0x142, 0xf, 0xf, false);  // row_bcast15
  x = fmaxf(x, __int_as_float(o)); xi = __float_as_int(x);
  o = __builtin_amdgcn_update_dpp(xi, xi, 0x143, 0xf, 0xf, false);  // row_bcast31
  x = fmaxf(x, __int_as_float(o)); xi = __float_as_int(x);
  return __int_as_float(__builtin_amdgcn_readlane(xi, 63));
}

// ---------------------------------------------------------------- FPS
// One block (1024 thr = 16 waves) per batch; thread t owns points
// [t*8, t*8+8) in registers. r12 measured VGPR_Count=36: the compiler kept
// only dist[8]+scalars and REMATERIALIZED px/py/pz from global (L2) every
// iteration — 6 loads + vmcnt waits on the serial critical path. Fix: pin
// the arrays in VGPRs with empty asm ("+v") right after init; the asm
// nominally modifies the values, so reloading from memory is illegal and
// the allocator must keep them resident (~64-72 VGPR, well under the
// 128/wave budget at 4 waves/SIMD).
// Everything else as r12: serial argmax fused in the update (best/bi
// scalars — low pressure, r9 lesson); DPP wave max; owner lane
// (ballot+ffsll, lane order == index order => first-occurrence argmax);
// float4 winner slot; parity-buffered LDS; ONE barrier; 16-slot scan.
__global__ __launch_bounds__(1024) void k_fps(const float* __restrict__ xyz,
                                              float* __restrict__ out_xyz,
                                              float* __restrict__ out_idx) {
  const int b = blockIdx.x;
  const int t = threadIdx.x;
  const float* xb = xyz + (size_t)b * NPB * 3;

  float px[8], py[8], pz[8], dist[8];
  {
    const float4* gp = reinterpret_cast<const float4*>(xb + (size_t)t * 24);
    float comp[24];
#pragma unroll
    for (int v = 0; v < 6; ++v) {
      float4 r = gp[v];
      comp[v * 4 + 0] = r.x;
      comp[v * 4 + 1] = r.y;
      comp[v * 4 + 2] = r.z;
      comp[v * 4 + 3] = r.w;
    }
#pragma unroll
    for (int j = 0; j < 8; ++j) {
      px[j] = comp[3 * j + 0];
      py[j] = comp[3 * j + 1];
      pz[j] = comp[3 * j + 2];
      dist[j] = 1e10f;
    }
  }
  // Pin coordinates in VGPRs (defeat rematerialization-from-global).
  asm volatile("" : "+v"(px[0]), "+v"(px[1]), "+v"(px[2]), "+v"(px[3]),
                    "+v"(px[4]), "+v"(px[5]), "+v"(px[6]), "+v"(px[7]));
  asm volatile("" : "+v"(py[0]), "+v"(py[1]), "+v"(py[2]), "+v"(py[3]),
                    "+v"(py[4]), "+v"(py[5]), "+v"(py[6]), "+v"(py[7]));
  asm volatile("" : "+v"(pz[0]), "+v"(pz[1]), "+v"(pz[2]), "+v"(pz[3]),
                    "+v"(pz[4]), "+v"(pz[5]), "+v"(pz[6]), "+v"(pz[7]));

  __shared__ __align__(16) float sD[2][16];
  __shared__ __align__(16) float4 sV[2][16];  // {x, y, z, idx_as_float}

  const int wid = t >> 6;
  const int lane = t & 63;

  // selection 0 = index 0; q broadcast via (L2-hot) global read by all lanes
  float qx = xb[0], qy = xb[1], qz = xb[2];
  if (t == 0) {
    out_idx[b * NPOINT + 0] = 0.0f;
    size_t o = (size_t)(b * NPOINT) * 3;
    out_xyz[o + 0] = qx; out_xyz[o + 1] = qy; out_xyz[o + 2] = qz;
  }

  for (int it = 1; it < NPOINT; ++it) {
    // exact per-point update + serial argmax (strict > keeps smallest j)
    float best = -1.0f;
    int bi = 0;
#pragma unroll
    for (int j = 0; j < 8; ++j) {
      float dx = __fsub_rn(px[j], qx);
      float dy = __fsub_rn(py[j], qy);
      float dz = __fsub_rn(pz[j], qz);
      float d2 = __fadd_rn(__fadd_rn(__fmul_rn(dx, dx), __fmul_rn(dy, dy)), __fmul_rn(dz, dz));
      float nd = fminf(dist[j], d2);
      dist[j] = nd;
      if (nd > best) { best = nd; bi = j; }
    }

    // wave-level f32 max (DPP; all lanes get wmax via readlane broadcast)
    const float wmax = wave_max_f32(best);
    const unsigned long long m = __ballot(best == wmax);
    const int p = it & 1;
    if (lane == (int)(__ffsll((unsigned long long)m) - 1)) {  // lowest tied lane
      sD[p][wid] = wmax;
      float sx_, sy_, sz_;
      switch (bi) {
        case 0:  sx_ = px[0]; sy_ = py[0]; sz_ = pz[0]; break;
        case 1:  sx_ = px[1]; sy_ = py[1]; sz_ = pz[1]; break;
        case 2:  sx_ = px[2]; sy_ = py[2]; sz_ = pz[2]; break;
        case 3:  sx_ = px[3]; sy_ = py[3]; sz_ = pz[3]; break;
        case 4:  sx_ = px[4]; sy_ = py[4]; sz_ = pz[4]; break;
        case 5:  sx_ = px[5]; sy_ = py[5]; sz_ = pz[5]; break;
        case 6:  sx_ = px[6]; sy_ = py[6]; sz_ = pz[6]; break;
        default: sx_ = px[7]; sy_ = py[7]; sz_ = pz[7]; break;
      }
      sV[p][wid] = make_float4(sx_, sy_, sz_, (float)(t * 8 + bi));
    }
    __syncthreads();  // the only barrier per iteration
    // every thread scans the 16 wave winners (strict > => smallest wid on tie)
    const float4 d0 = *reinterpret_cast<const float4*>(&sD[p][0]);
    const float4 d1 = *reinterpret_cast<const float4*>(&sD[p][4]);
    const float4 d2 = *reinterpret_cast<const float4*>(&sD[p][8]);
    const float4 d3 = *reinterpret_cast<const float4*>(&sD[p][12]);
    float bd = d0.x;
    int bw = 0;
    if (d0.y > bd) { bd = d0.y; bw = 1; }
    if (d0.z > bd) { bd = d0.z; bw = 2; }
    if (d0.w > bd) { bd = d0.w; bw = 3; }
    if (d1.x > bd) { bd = d1.x; bw = 4; }
    if (d1.y > bd) { bd = d1.y; bw = 5; }
    if (d1.z > bd) { bd = d1.z; bw = 6; }
    if (d1.w > bd) { bd = d1.w; bw = 7; }
    if (d2.x > bd) { bd = d2.x; bw = 8; }
    if (d2.y > bd) { bd = d2.y; bw = 9; }
    if (d2.z > bd) { bd = d2.z; bw = 10; }
    if (d2.w > bd) { bd = d2.w; bw = 11; }
    if (d3.x > bd) { bd = d3.x; bw = 12; }
    if (d3.y > bd) { bd = d3.y; bw = 13; }
    if (d3.z > bd) { bd = d3.z; bw = 14; }
    if (d3.w > bd) { bd = d3.w; bw = 15; }
    const float4 wv = sV[p][bw];  // broadcast read (same addr all lanes)
    qx = wv.x; qy = wv.y; qz = wv.z;
    if (t == 0) {
      out_idx[b * NPOINT + it] = wv.w;
      size_t o = (size_t)(b * NPOINT + it) * 3;
      out_xyz[o + 0] = qx; out_xyz[o + 1] = qy; out_xyz[o + 2] = qz;
    }
  }
}

// ---------------------------------------------------------- feature transpose
// features f32 [64][Ntot] -> feat_t bf16 [Ntot][64]
__global__ __launch_bounds__(256) void k_transpose(const float* __restrict__ in,
                                                   unsigned short* __restrict__ out,
                                                   int Ntot) {
  __shared__ __align__(16) unsigned short tile[64][65];
  const int t = threadIdx.x;
  const int n0 = blockIdx.x * 64;
#pragma unroll
  for (int i = 0; i < 16; ++i) {
    int c = i * 4 + (t >> 6);
    int n = t & 63;
    tile[c][n] = f2bf(in[(size_t)c * Ntot + n0 + n]);
  }
  __syncthreads();
#pragma unroll
  for (int i = 0; i < 16; ++i) {
    int n = i * 4 + (t >> 6);
    int c = t & 63;
    out[(size_t)(n0 + n) * 64 + c] = tile[c][n];
  }
}

// ---------------------------------------------------------------- ball query
// One wave per center (8 waves/block). Fixed 64 rounds x 2 points/lane: no
// data-dependent loop condition, so loads pipeline across rounds. Ordered
// compaction via ballot+popcount (first-64 sub-block before second-64 keeps
// index order). Exact f32 math, strict <.
__global__ __launch_bounds__(512) void k_ball(const float* __restrict__ xyz,
                                              const float* __restrict__ fps_idx_f,
                                              float* __restrict__ sids_f) {
  __shared__ int slots[8 * NSAMPLE];
  const int b = blockIdx.x >> 6;
  const int cbase = (blockIdx.x & 63) * 8;
  const int t = threadIdx.x;
  const float* xb = xyz + (size_t)b * NPB * 3;

  const int w = t >> 6, lane = t & 63;
  const int c_local = cbase + w;
  const int ci = (int)fps_idx_f[b * NPOINT + c_local];
  const float cx = xb[ci * 3 + 0];
  const float cy = xb[ci * 3 + 1];
  const float cz = xb[ci * 3 + 2];
  const float R2 = 0.01f;  // f32(0.1*0.1), numpy weak-scalar promotion
  const unsigned long long below = (1ull << lane) - 1ull;

  int cnt = 0;
#pragma unroll 4
  for (int r = 0; r < 64; ++r) {
    const int p0 = r * 128 + lane;
    const int p1 = p0 + 64;
    float ax = xb[p0 * 3 + 0], ay = xb[p0 * 3 + 1], az = xb[p0 * 3 + 2];
    float bx = xb[p1 * 3 + 0], by = xb[p1 * 3 + 1], bz = xb[p1 * 3 + 2];
    float dxa = __fsub_rn(ax, cx), dya = __fsub_rn(ay, cy), dza = __fsub_rn(az, cz);
    float dxb = __fsub_rn(bx, cx), dyb = __fsub_rn(by, cy), dzb = __fsub_rn(bz, cz);
    float d2a = __fadd_rn(__fadd_rn(__fmul_rn(dxa, dxa), __fmul_rn(dya, dya)), __fmul_rn(dza, dza));
    float d2b = __fadd_rn(__fadd_rn(__fmul_rn(dxb, dxb), __fmul_rn(dyb, dyb)), __fmul_rn(dzb, dzb));
    const bool i0 = d2a < R2;
    const bool i1 = d2b < R2;
    const unsigned long long m0 = __ballot(i0);
    if (i0) {
      int pos = cnt + (int)__popcll(m0 & below);
      if (pos < NSAMPLE) slots[w * NSAMPLE + pos] = p0;
    }
    cnt += (int)__popcll(m0);
    const unsigned long long m1 = __ballot(i1);
    if (i1) {
      int pos = cnt + (int)__popcll(m1 & below);
      if (pos < NSAMPLE) slots[w * NSAMPLE + pos] = p1;
    }
    cnt += (int)__popcll(m1);
  }
  if (lane < NSAMPLE) {
    const int first = (cnt > 0) ? slots[w * NSAMPLE] : 0;
    const int v = (lane < cnt) ? slots[w * NSAMPLE + lane] : first;
    sids_f[((size_t)(b * NPOINT + c_local)) * NSAMPLE + lane] = (float)v;
  }
}

// ------------------------------------------------------- gather + MLP + max
// 32 lanes = 32 samples, 2 centers per wave, 8 centers per 256-thr block.
// W0/W2 f32 in LDS, W1 bf16 in LDS (~59 KB). h1/h2 in registers.
__global__ __launch_bounds__(256) void k_mlp(const float* __restrict__ xyz,
                                             const float* __restrict__ feat,
                                             const unsigned short* __restrict__ feat_t,
                                             const float* __restrict__ fps_idx_f,
                                             const float* __restrict__ sids_f,
                                             const float* __restrict__ w0g,
                                             const float* __restrict__ b0g,
                                             const float* __restrict__ w1g,
                                             const float* __restrict__ b1g,
                                             const float* __restrict__ w2g,
                                             const float* __restrict__ b2g,
                                             float* __restrict__ out_feat,
                                             int Ntot, int useT) {
  __shared__ __align__(16) float W0s[64 * 68];            // padded rows (c 67 = 0)
  __shared__ __align__(16) unsigned short W1s[64 * 64];   // bf16
  __shared__ __align__(16) float W2s[128 * 64];
  __shared__ float b0s[64], b1s[64], b2s[128];
  const int t = threadIdx.x;
  for (int i = t; i < 64 * 68; i += 256) {
    int r = i / 68, c = i - r * 68;
    W0s[i] = (c < 67) ? w0g[r * 67 + c] : 0.0f;
  }
  for (int i = t; i < 64 * 64; i += 256) W1s[i] = f2bf(w1g[i]);
  for (int i = t; i < 128 * 64; i += 256) W2s[i] = w2g[i];
  if (t < 64) b0s[t] = b0g[t];
  if (t < 64) b1s[t] = b1g[t];
  if (t < 128) b2s[t] = b2g[t];
  __syncthreads();

  const int b = blockIdx.x >> 6;
  const int c_local = (blockIdx.x & 63) * 8 + (t >> 5);
  const int s = t & 31;
  const int ci = (int)fps_idx_f[b * NPOINT + c_local];
  const float cx = xyz[((size_t)b * NPB + ci) * 3 + 0];
  const float cy = xyz[((size_t)b * NPB + ci) * 3 + 1];
  const float cz = xyz[((size_t)b * NPB + ci) * 3 + 2];
  const int id = (int)sids_f[((size_t)(b * NPOINT + c_local)) * NSAMPLE + s];

  float g[68];
  {
    const size_t pb = ((size_t)b * NPB + id) * 3;
    g[0] = __fsub_rn(xyz[pb + 0], cx);
    g[1] = __fsub_rn(xyz[pb + 1], cy);
    g[2] = __fsub_rn(xyz[pb + 2], cz);
    if (useT) {
      const uint4* fp = reinterpret_cast<const uint4*>(feat_t + ((size_t)b * NPB + id) * 64);
#pragma unroll
      for (int v = 0; v < 8; ++v) {
        uint4 r = fp[v];
        unsigned int vs[4] = {r.x, r.y, r.z, r.w};
#pragma unroll
        for (int q = 0; q < 4; ++q) {
          g[3 + v * 8 + q * 2 + 0] = __uint_as_float(vs[q] << 16);
          g[3 + v * 8 + q * 2 + 1] = __uint_as_float(vs[q] & 0xFFFF0000u);
        }
      }
    } else {
      const float* col = feat + (size_t)(b * NPB + id);
#pragma unroll 8
      for (int c = 0; c < 64; ++c) g[3 + c] = col[(size_t)c * Ntot];
    }
    g[67] = 0.0f;
  }

  float h1[64];
#pragma unroll
  for (int o = 0; o < 64; ++o) {
    float acc = b0s[o];
    const float4* wp = reinterpret_cast<const float4*>(&W0s[o * 68]);
#pragma unroll
    for (int c4 = 0; c4 < 17; ++c4) {
      float4 wv = wp[c4];
      acc += wv.x * g[c4 * 4 + 0];
      acc += wv.y * g[c4 * 4 + 1];
      acc += wv.z * g[c4 * 4 + 2];
      acc += wv.w * g[c4 * 4 + 3];
    }
    h1[o] = fmaxf(acc, 0.0f);
  }
  float h2[64];
#pragma unroll
  for (int o = 0; o < 64; ++o) {
    float acc = b1s[o];
    const uint2* wp = reinterpret_cast<const uint2*>(&W1s[o * 64]);
#pragma unroll
    for (int c4 = 0; c4 < 16; ++c4) {
      uint2 u = wp[c4];
      acc += __uint_as_float(u.x << 16) * h1[c4 * 4 + 0];
      acc += __uint_as_float(u.x & 0xFFFF0000u) * h1[c4 * 4 + 1];
      acc += __uint_as_float(u.y << 16) * h1[c4 * 4 + 2];
      acc += __uint_as_float(u.y & 0xFFFF0000u) * h1[c4 * 4 + 3];
    }
    h2[o] = fmaxf(acc, 0.0f);
  }
#pragma unroll 1
  for (int o = 0; o < 128; ++o) {
    float acc = b2s[o];
    const float4* wp = reinterpret_cast<const float4*>(&W2s[o * 64]);
#pragma unroll
    for (int c4 = 0; c4 < 16; ++c4) {
      float4 wv = wp[c4];
      acc += wv.x * h2[c4 * 4 + 0];
      acc += wv.y * h2[c4 * 4 + 1];
      acc += wv.z * h2[c4 * 4 + 2];
      acc += wv.w * h2[c4 * 4 + 3];
    }
    float v = fmaxf(acc, 0.0f);
#pragma unroll
    for (int off = 16; off >= 1; off >>= 1) v = fmaxf(v, __shfl_xor(v, off));
    if (s == 0) out_feat[((size_t)b * 128 + o) * NPOINT + c_local] = v;
  }
}

// ------------------------------------------------------------------- launch
extern "C" void kernel_launch(void* const* d_in, const int* in_sizes, int n_in,
                              void* d_out, int out_size, void* d_ws, size_t ws_size,
                              hipStream_t stream) {
  (void)n_in; (void)out_size;
  const float* xyz = (const float*)d_in[0];
  const float* feat = (const float*)d_in[1];
  // d_in[2] = num_points (8192, fixed by setup)
  const float* w0 = (const float*)d_in[3];
  const float* b0 = (const float*)d_in[4];
  const float* w1 = (const float*)d_in[5];
  const float* b1 = (const float*)d_in[6];
  const float* w2 = (const float*)d_in[7];
  const float* b2 = (const float*)d_in[8];

  const int Ntot = in_sizes[0] / 3;   // 65536
  const int B = Ntot / NPB;           // 8

  float* out = (float*)d_out;
  float* o_xyz = out;                                    // [B,512,3]
  float* o_idx = o_xyz + (size_t)B * NPOINT * 3;         // [B,512]
  float* o_feat = o_idx + (size_t)B * NPOINT;            // [B,128,512]
  float* o_sids = o_feat + (size_t)B * 128 * NPOINT;     // [B,512,32]

  // Workspace: only the transposed-features buffer (bf16), only if it fits.
  const size_t ft_bytes = (size_t)Ntot * 64 * 2;         // 8 MB
  const int useT = (ws_size >= ft_bytes) ? 1 : 0;
  unsigned short* ft_ws = (unsigned short*)d_ws;

  if (useT) {
    k_transpose<<<dim3(Ntot / 64), dim3(256), 0, stream>>>(feat, ft_ws, Ntot);
  }
  k_fps<<<dim3(B), dim3(1024), 0, stream>>>(xyz, o_xyz, o_idx);
  k_ball<<<dim3(B * 64), dim3(512), 0, stream>>>(xyz, o_idx, o_sids);
  k_mlp<<<dim3(B * 64), dim3(256), 0, stream>>>(xyz, feat, ft_ws, o_idx, o_sids,
                                                w0, b0, w1, b1, w2, b2, o_feat,
                                                Ntot, useT);
}

// Round 14
// 806.310 us; speedup vs baseline: 2.1851x; 1.0910x over previous
//
#include <hip/hip_runtime.h>
#include <cstdint>
#include <cstddef>

#define NPOINT 512
#define NSAMPLE 32
#define NPB 8192  // points per batch

// Inputs: float32. Outputs: float32 flat concat (new_xyz, new_idx,
// new_features, sample_ids). Selection math (FPS argmax, ball d2<r2) must be
// bit-exact vs numpy f32: __f*_rn ops, no FMA contraction, exact tie-breaks.
__device__ __forceinline__ unsigned short f2bf(float f) {
  unsigned int u = __float_as_uint(f);
  unsigned int r = u + 0x7FFFu + ((u >> 16) & 1u);  // RNE
  return (unsigned short)(r >> 16);
}

// Wave64 f32 max via DPP (VALU-only). Canonical rocPRIM sequence; lane 63
// ends with the full wave max, readlane(63) broadcasts. bound_ctrl=false
// with old=src => sourceless lanes compute fmax(x,x)=x (harmless).
// Validated r9/r12: bank conflicts 0, tiny LDS, correct results.
__device__ __forceinline__ float wave_max_f32(float x) {
  int xi = __float_as_int(x);
  int o;
  o = __builtin_amdgcn_update_dpp(xi, xi, 0xb1, 0xf, 0xf, false);   // quad_perm [1,0,3,2]
  x = fmaxf(x, __int_as_float(o)); xi = __float_as_int(x);
  o = __builtin_amdgcn_update_dpp(xi, xi, 0x4e, 0xf, 0xf, false);   // quad_perm [2,3,0,1]
  x = fmaxf(x, __int_as_float(o)); xi = __float_as_int(x);
  o = __builtin_amdgcn_update_dpp(xi, xi, 0x141, 0xf, 0xf, false);  // row_half_mirror
  x = fmaxf(x, __int_as_float(o)); xi = __float_as_int(x);
  o = __builtin_amdgcn_update_dpp(xi, xi, 0x140, 0xf, 0xf, false);  // row_mirror
  x = fmaxf(x, __int_as_float(o)); xi = __float_as_int(x);
  o = __builtin_amdgcn_update_dpp(xi, xi, 0x142, 0xf, 0xf, false);  // row_bcast15
  x = fmaxf(x, __int_as_float(o)); xi = __float_as_int(x);
  o = __builtin_amdgcn_update_dpp(xi, xi, 0x143, 0xf, 0xf, false);  // row_bcast31
  x = fmaxf(x, __int_as_float(o)); xi = __float_as_int(x);
  return __int_as_float(__builtin_amdgcn_readlane(xi, 63));
}

// ---------------------------------------------------------------- FPS
// MATRIX CELL NEVER MEASURED: 512 thr x 16 pts (the ONE config proven to
// keep px/py/pz/dist resident in real VGPRs: baseline compiled at 72 VGPR,
// zero spill, 636us) + SERIAL argmax (low pressure, r9 lesson) + DPP
// reduce (r12-validated, ~50cy vs ~700cy ds_bpermute chain).
// History: r4-r8 paired DPP with tree argmax -> VGPR 56, spill, 1528us.
// r12/r13 paired serial argmax with 1024thr/8pts -> compiler parked arrays
// in AGPRs (VGPR 32-36), accvgpr traffic ate the DPP gain, 644us (= the
// 636us ds_bpermute baseline). This isolates the reduce-latency variable
// on the resident-array body.
// Per iteration: exact dist update + serial argmax; DPP wave max; owner
// lane (ballot+ffsll; lane order == index order => jnp.argmax
// first-occurrence) publishes wmax + {x,y,z,idx} float4 to parity LDS;
// ONE barrier; all threads scan 8 wave maxima (strict > keeps smallest
// wid) and read the winner's float4.
__global__ __launch_bounds__(512) void k_fps(const float* __restrict__ xyz,
                                             float* __restrict__ out_xyz,
                                             float* __restrict__ out_idx) {
  const int b = blockIdx.x;
  const int t = threadIdx.x;
  const float* xb = xyz + (size_t)b * NPB * 3;

  float px[16], py[16], pz[16], dist[16];
  {
    const float4* gp = reinterpret_cast<const float4*>(xb + (size_t)t * 48);
    float comp[48];
#pragma unroll
    for (int v = 0; v < 12; ++v) {
      float4 r = gp[v];
      comp[v * 4 + 0] = r.x;
      comp[v * 4 + 1] = r.y;
      comp[v * 4 + 2] = r.z;
      comp[v * 4 + 3] = r.w;
    }
#pragma unroll
    for (int j = 0; j < 16; ++j) {
      px[j] = comp[3 * j + 0];
      py[j] = comp[3 * j + 1];
      pz[j] = comp[3 * j + 2];
      dist[j] = 1e10f;
    }
  }

  __shared__ __align__(16) float sD[2][8];
  __shared__ __align__(16) float4 sV[2][8];  // {x, y, z, idx_as_float}

  const int wid = t >> 6;
  const int lane = t & 63;

  // selection 0 = index 0; q broadcast via (L2-hot) global read by all lanes
  float qx = xb[0], qy = xb[1], qz = xb[2];
  if (t == 0) {
    out_idx[b * NPOINT + 0] = 0.0f;
    size_t o = (size_t)(b * NPOINT) * 3;
    out_xyz[o + 0] = qx; out_xyz[o + 1] = qy; out_xyz[o + 2] = qz;
  }

  for (int it = 1; it < NPOINT; ++it) {
    // exact per-point update + serial argmax (strict > keeps smallest j)
    float best = -1.0f;
    int bi = 0;
#pragma unroll
    for (int j = 0; j < 16; ++j) {
      float dx = __fsub_rn(px[j], qx);
      float dy = __fsub_rn(py[j], qy);
      float dz = __fsub_rn(pz[j], qz);
      float d2 = __fadd_rn(__fadd_rn(__fmul_rn(dx, dx), __fmul_rn(dy, dy)), __fmul_rn(dz, dz));
      float nd = fminf(dist[j], d2);
      dist[j] = nd;
      if (nd > best) { best = nd; bi = j; }
    }

    // wave-level f32 max (DPP; all lanes get wmax via readlane broadcast)
    const float wmax = wave_max_f32(best);
    const unsigned long long m = __ballot(best == wmax);
    const int p = it & 1;
    if (lane == (int)(__ffsll((unsigned long long)m) - 1)) {  // lowest tied lane
      sD[p][wid] = wmax;
      float sx_, sy_, sz_;
      switch (bi) {
        case 0:  sx_ = px[0];  sy_ = py[0];  sz_ = pz[0];  break;
        case 1:  sx_ = px[1];  sy_ = py[1];  sz_ = pz[1];  break;
        case 2:  sx_ = px[2];  sy_ = py[2];  sz_ = pz[2];  break;
        case 3:  sx_ = px[3];  sy_ = py[3];  sz_ = pz[3];  break;
        case 4:  sx_ = px[4];  sy_ = py[4];  sz_ = pz[4];  break;
        case 5:  sx_ = px[5];  sy_ = py[5];  sz_ = pz[5];  break;
        case 6:  sx_ = px[6];  sy_ = py[6];  sz_ = pz[6];  break;
        case 7:  sx_ = px[7];  sy_ = py[7];  sz_ = pz[7];  break;
        case 8:  sx_ = px[8];  sy_ = py[8];  sz_ = pz[8];  break;
        case 9:  sx_ = px[9];  sy_ = py[9];  sz_ = pz[9];  break;
        case 10: sx_ = px[10]; sy_ = py[10]; sz_ = pz[10]; break;
        case 11: sx_ = px[11]; sy_ = py[11]; sz_ = pz[11]; break;
        case 12: sx_ = px[12]; sy_ = py[12]; sz_ = pz[12]; break;
        case 13: sx_ = px[13]; sy_ = py[13]; sz_ = pz[13]; break;
        case 14: sx_ = px[14]; sy_ = py[14]; sz_ = pz[14]; break;
        default: sx_ = px[15]; sy_ = py[15]; sz_ = pz[15]; break;
      }
      sV[p][wid] = make_float4(sx_, sy_, sz_, (float)(t * 16 + bi));
    }
    __syncthreads();  // the only barrier per iteration
    // every thread scans the 8 wave winners (strict > => smallest wid on tie)
    const float4 d0 = *reinterpret_cast<const float4*>(&sD[p][0]);
    const float4 d1 = *reinterpret_cast<const float4*>(&sD[p][4]);
    float bd = d0.x;
    int bw = 0;
    if (d0.y > bd) { bd = d0.y; bw = 1; }
    if (d0.z > bd) { bd = d0.z; bw = 2; }
    if (d0.w > bd) { bd = d0.w; bw = 3; }
    if (d1.x > bd) { bd = d1.x; bw = 4; }
    if (d1.y > bd) { bd = d1.y; bw = 5; }
    if (d1.z > bd) { bd = d1.z; bw = 6; }
    if (d1.w > bd) { bd = d1.w; bw = 7; }
    const float4 wv = sV[p][bw];  // broadcast read (same addr all lanes)
    qx = wv.x; qy = wv.y; qz = wv.z;
    if (t == 0) {
      out_idx[b * NPOINT + it] = wv.w;
      size_t o = (size_t)(b * NPOINT + it) * 3;
      out_xyz[o + 0] = qx; out_xyz[o + 1] = qy; out_xyz[o + 2] = qz;
    }
  }
}

// ---------------------------------------------------------- feature transpose
// features f32 [64][Ntot] -> feat_t bf16 [Ntot][64]
__global__ __launch_bounds__(256) void k_transpose(const float* __restrict__ in,
                                                   unsigned short* __restrict__ out,
                                                   int Ntot) {
  __shared__ __align__(16) unsigned short tile[64][65];
  const int t = threadIdx.x;
  const int n0 = blockIdx.x * 64;
#pragma unroll
  for (int i = 0; i < 16; ++i) {
    int c = i * 4 + (t >> 6);
    int n = t & 63;
    tile[c][n] = f2bf(in[(size_t)c * Ntot + n0 + n]);
  }
  __syncthreads();
#pragma unroll
  for (int i = 0; i < 16; ++i) {
    int n = i * 4 + (t >> 6);
    int c = t & 63;
    out[(size_t)(n0 + n) * 64 + c] = tile[c][n];
  }
}

// ---------------------------------------------------------------- ball query
// One wave per center (8 waves/block). Fixed 64 rounds x 2 points/lane: no
// data-dependent loop condition, so loads pipeline across rounds. Ordered
// compaction via ballot+popcount (first-64 sub-block before second-64 keeps
// index order). Exact f32 math, strict <.
__global__ __launch_bounds__(512) void k_ball(const float* __restrict__ xyz,
                                              const float* __restrict__ fps_idx_f,
                                              float* __restrict__ sids_f) {
  __shared__ int slots[8 * NSAMPLE];
  const int b = blockIdx.x >> 6;
  const int cbase = (blockIdx.x & 63) * 8;
  const int t = threadIdx.x;
  const float* xb = xyz + (size_t)b * NPB * 3;

  const int w = t >> 6, lane = t & 63;
  const int c_local = cbase + w;
  const int ci = (int)fps_idx_f[b * NPOINT + c_local];
  const float cx = xb[ci * 3 + 0];
  const float cy = xb[ci * 3 + 1];
  const float cz = xb[ci * 3 + 2];
  const float R2 = 0.01f;  // f32(0.1*0.1), numpy weak-scalar promotion
  const unsigned long long below = (1ull << lane) - 1ull;

  int cnt = 0;
#pragma unroll 4
  for (int r = 0; r < 64; ++r) {
    const int p0 = r * 128 + lane;
    const int p1 = p0 + 64;
    float ax = xb[p0 * 3 + 0], ay = xb[p0 * 3 + 1], az = xb[p0 * 3 + 2];
    float bx = xb[p1 * 3 + 0], by = xb[p1 * 3 + 1], bz = xb[p1 * 3 + 2];
    float dxa = __fsub_rn(ax, cx), dya = __fsub_rn(ay, cy), dza = __fsub_rn(az, cz);
    float dxb = __fsub_rn(bx, cx), dyb = __fsub_rn(by, cy), dzb = __fsub_rn(bz, cz);
    float d2a = __fadd_rn(__fadd_rn(__fmul_rn(dxa, dxa), __fmul_rn(dya, dya)), __fmul_rn(dza, dza));
    float d2b = __fadd_rn(__fadd_rn(__fmul_rn(dxb, dxb), __fmul_rn(dyb, dyb)), __fmul_rn(dzb, dzb));
    const bool i0 = d2a < R2;
    const bool i1 = d2b < R2;
    const unsigned long long m0 = __ballot(i0);
    if (i0) {
      int pos = cnt + (int)__popcll(m0 & below);
      if (pos < NSAMPLE) slots[w * NSAMPLE + pos] = p0;
    }
    cnt += (int)__popcll(m0);
    const unsigned long long m1 = __ballot(i1);
    if (i1) {
      int pos = cnt + (int)__popcll(m1 & below);
      if (pos < NSAMPLE) slots[w * NSAMPLE + pos] = p1;
    }
    cnt += (int)__popcll(m1);
  }
  if (lane < NSAMPLE) {
    const int first = (cnt > 0) ? slots[w * NSAMPLE] : 0;
    const int v = (lane < cnt) ? slots[w * NSAMPLE + lane] : first;
    sids_f[((size_t)(b * NPOINT + c_local)) * NSAMPLE + lane] = (float)v;
  }
}

// ------------------------------------------------------- gather + MLP + max
// 32 lanes = 32 samples, 2 centers per wave, 8 centers per 256-thr block.
// W0/W2 f32 in LDS, W1 bf16 in LDS (~59 KB). h1/h2 in registers.
__global__ __launch_bounds__(256) void k_mlp(const float* __restrict__ xyz,
                                             const float* __restrict__ feat,
                                             const unsigned short* __restrict__ feat_t,
                                             const float* __restrict__ fps_idx_f,
                                             const float* __restrict__ sids_f,
                                             const float* __restrict__ w0g,
                                             const float* __restrict__ b0g,
                                             const float* __restrict__ w1g,
                                             const float* __restrict__ b1g,
                                             const float* __restrict__ w2g,
                                             const float* __restrict__ b2g,
                                             float* __restrict__ out_feat,
                                             int Ntot, int useT) {
  __shared__ __align__(16) float W0s[64 * 68];            // padded rows (c 67 = 0)
  __shared__ __align__(16) unsigned short W1s[64 * 64];   // bf16
  __shared__ __align__(16) float W2s[128 * 64];
  __shared__ float b0s[64], b1s[64], b2s[128];
  const int t = threadIdx.x;
  for (int i = t; i < 64 * 68; i += 256) {
    int r = i / 68, c = i - r * 68;
    W0s[i] = (c < 67) ? w0g[r * 67 + c] : 0.0f;
  }
  for (int i = t; i < 64 * 64; i += 256) W1s[i] = f2bf(w1g[i]);
  for (int i = t; i < 128 * 64; i += 256) W2s[i] = w2g[i];
  if (t < 64) b0s[t] = b0g[t];
  if (t < 64) b1s[t] = b1g[t];
  if (t < 128) b2s[t] = b2g[t];
  __syncthreads();

  const int b = blockIdx.x >> 6;
  const int c_local = (blockIdx.x & 63) * 8 + (t >> 5);
  const int s = t & 31;
  const int ci = (int)fps_idx_f[b * NPOINT + c_local];
  const float cx = xyz[((size_t)b * NPB + ci) * 3 + 0];
  const float cy = xyz[((size_t)b * NPB + ci) * 3 + 1];
  const float cz = xyz[((size_t)b * NPB + ci) * 3 + 2];
  const int id = (int)sids_f[((size_t)(b * NPOINT + c_local)) * NSAMPLE + s];

  float g[68];
  {
    const size_t pb = ((size_t)b * NPB + id) * 3;
    g[0] = __fsub_rn(xyz[pb + 0], cx);
    g[1] = __fsub_rn(xyz[pb + 1], cy);
    g[2] = __fsub_rn(xyz[pb + 2], cz);
    if (useT) {
      const uint4* fp = reinterpret_cast<const uint4*>(feat_t + ((size_t)b * NPB + id) * 64);
#pragma unroll
      for (int v = 0; v < 8; ++v) {
        uint4 r = fp[v];
        unsigned int vs[4] = {r.x, r.y, r.z, r.w};
#pragma unroll
        for (int q = 0; q < 4; ++q) {
          g[3 + v * 8 + q * 2 + 0] = __uint_as_float(vs[q] << 16);
          g[3 + v * 8 + q * 2 + 1] = __uint_as_float(vs[q] & 0xFFFF0000u);
        }
      }
    } else {
      const float* col = feat + (size_t)(b * NPB + id);
#pragma unroll 8
      for (int c = 0; c < 64; ++c) g[3 + c] = col[(size_t)c * Ntot];
    }
    g[67] = 0.0f;
  }

  float h1[64];
#pragma unroll
  for (int o = 0; o < 64; ++o) {
    float acc = b0s[o];
    const float4* wp = reinterpret_cast<const float4*>(&W0s[o * 68]);
#pragma unroll
    for (int c4 = 0; c4 < 17; ++c4) {
      float4 wv = wp[c4];
      acc += wv.x * g[c4 * 4 + 0];
      acc += wv.y * g[c4 * 4 + 1];
      acc += wv.z * g[c4 * 4 + 2];
      acc += wv.w * g[c4 * 4 + 3];
    }
    h1[o] = fmaxf(acc, 0.0f);
  }
  float h2[64];
#pragma unroll
  for (int o = 0; o < 64; ++o) {
    float acc = b1s[o];
    const uint2* wp = reinterpret_cast<const uint2*>(&W1s[o * 64]);
#pragma unroll
    for (int c4 = 0; c4 < 16; ++c4) {
      uint2 u = wp[c4];
      acc += __uint_as_float(u.x << 16) * h1[c4 * 4 + 0];
      acc += __uint_as_float(u.x & 0xFFFF0000u) * h1[c4 * 4 + 1];
      acc += __uint_as_float(u.y << 16) * h1[c4 * 4 + 2];
      acc += __uint_as_float(u.y & 0xFFFF0000u) * h1[c4 * 4 + 3];
    }
    h2[o] = fmaxf(acc, 0.0f);
  }
#pragma unroll 1
  for (int o = 0; o < 128; ++o) {
    float acc = b2s[o];
    const float4* wp = reinterpret_cast<const float4*>(&W2s[o * 64]);
#pragma unroll
    for (int c4 = 0; c4 < 16; ++c4) {
      float4 wv = wp[c4];
      acc += wv.x * h2[c4 * 4 + 0];
      acc += wv.y * h2[c4 * 4 + 1];
      acc += wv.z * h2[c4 * 4 + 2];
      acc += wv.w * h2[c4 * 4 + 3];
    }
    float v = fmaxf(acc, 0.0f);
#pragma unroll
    for (int off = 16; off >= 1; off >>= 1) v = fmaxf(v, __shfl_xor(v, off));
    if (s == 0) out_feat[((size_t)b * 128 + o) * NPOINT + c_local] = v;
  }
}

// ------------------------------------------------------------------- launch
extern "C" void kernel_launch(void* const* d_in, const int* in_sizes, int n_in,
                              void* d_out, int out_size, void* d_ws, size_t ws_size,
                              hipStream_t stream) {
  (void)n_in; (void)out_size;
  const float* xyz = (const float*)d_in[0];
  const float* feat = (const float*)d_in[1];
  // d_in[2] = num_points (8192, fixed by setup)
  const float* w0 = (const float*)d_in[3];
  const float* b0 = (const float*)d_in[4];
  const float* w1 = (const float*)d_in[5];
  const float* b1 = (const float*)d_in[6];
  const float* w2 = (const float*)d_in[7];
  const float* b2 = (const float*)d_in[8];

  const int Ntot = in_sizes[0] / 3;   // 65536
  const int B = Ntot / NPB;           // 8

  float* out = (float*)d_out;
  float* o_xyz = out;                                    // [B,512,3]
  float* o_idx = o_xyz + (size_t)B * NPOINT * 3;         // [B,512]
  float* o_feat = o_idx + (size_t)B * NPOINT;            // [B,128,512]
  float* o_sids = o_feat + (size_t)B * 128 * NPOINT;     // [B,512,32]

  // Workspace: only the transposed-features buffer (bf16), only if it fits.
  const size_t ft_bytes = (size_t)Ntot * 64 * 2;         // 8 MB
  const int useT = (ws_size >= ft_bytes) ? 1 : 0;
  unsigned short* ft_ws = (unsigned short*)d_ws;

  if (useT) {
    k_transpose<<<dim3(Ntot / 64), dim3(256), 0, stream>>>(feat, ft_ws, Ntot);
  }
  k_fps<<<dim3(B), dim3(512), 0, stream>>>(xyz, o_xyz, o_idx);
  k_ball<<<dim3(B * 64), dim3(512), 0, stream>>>(xyz, o_idx, o_sids);
  k_mlp<<<dim3(B * 64), dim3(256), 0, stream>>>(xyz, feat, ft_ws, o_idx, o_sids,
                                                w0, b0, w1, b1, w2, b2, o_feat,
                                                Ntot, useT);
}

// Round 15
// 806.007 us; speedup vs baseline: 2.1859x; 1.0004x over previous
//
#include <hip/hip_runtime.h>
#include <cstdint>
#include <cstddef>

#define NPOINT 512
#define NSAMPLE 32
#define NPB 8192  // points per batch

// Inputs: float32. Outputs: float32 flat concat (new_xyz, new_idx,
// new_features, sample_ids). Selection math (FPS argmax, ball d2<r2) must be
// bit-exact vs numpy f32: __f*_rn ops, no FMA contraction, exact tie-breaks.
__device__ __forceinline__ unsigned short f2bf(float f) {
  unsigned int u = __float_as_uint(f);
  unsigned int r = u + 0x7FFFu + ((u >> 16) & 1u);  // RNE
  return (unsigned short)(r >> 16);
}

// Wave64 f32 max via DPP (VALU-only). Canonical rocPRIM sequence; lane 63
// ends with the full wave max, readlane(63) broadcasts. bound_ctrl=false
// with old=src => sourceless lanes compute fmax(x,x)=x (harmless).
// Validated r9/r12/r14: bank conflicts 0, tiny LDS, correct results.
// r14 measured: DPP reduce on the 512thr/16pt body = 566us vs 636us for
// the ds_bpermute chain (-0.14us/iter).
__device__ __forceinline__ float wave_max_f32(float x) {
  int xi = __float_as_int(x);
  int o;
  o = __builtin_amdgcn_update_dpp(xi, xi, 0xb1, 0xf, 0xf, false);   // quad_perm [1,0,3,2]
  x = fmaxf(x, __int_as_float(o)); xi = __float_as_int(x);
  o = __builtin_amdgcn_update_dpp(xi, xi, 0x4e, 0xf, 0xf, false);   // quad_perm [2,3,0,1]
  x = fmaxf(x, __int_as_float(o)); xi = __float_as_int(x);
  o = __builtin_amdgcn_update_dpp(xi, xi, 0x141, 0xf, 0xf, false);  // row_half_mirror
  x = fmaxf(x, __int_as_float(o)); xi = __float_as_int(x);
  o = __builtin_amdgcn_update_dpp(xi, xi, 0x140, 0xf, 0xf, false);  // row_mirror
  x = fmaxf(x, __int_as_float(o)); xi = __float_as_int(x);
  o = __builtin_amdgcn_update_dpp(xi, xi, 0x142, 0xf, 0xf, false);  // row_bcast15
  x = fmaxf(x, __int_as_float(o)); xi = __float_as_int(x);
  o = __builtin_amdgcn_update_dpp(xi, xi, 0x143, 0xf, 0xf, false);  // row_bcast31
  x = fmaxf(x, __int_as_float(o)); xi = __float_as_int(x);
  return __int_as_float(__builtin_amdgcn_readlane(xi, 63));
}

// ---------------------------------------------------------------- FPS
// r14 winner (566us): 512 thr x 16 pts + serial argmax + DPP reduce +
// float4 winner slot + ONE barrier. This round's single delta:
// __launch_bounds__(512, 1) — only 8 blocks run on 256 CUs, so occupancy
// is irrelevant; the default bound capped VGPR at 56 and parked part of
// px/py/pz in AGPRs (unified file), adding accvgpr_read/write moves to
// every update iteration. min-waves=1 raises the budget to 256 VGPR so
// all 64 array values live in architectural VGPRs.
__global__ __launch_bounds__(512, 1) void k_fps(const float* __restrict__ xyz,
                                                float* __restrict__ out_xyz,
                                                float* __restrict__ out_idx) {
  const int b = blockIdx.x;
  const int t = threadIdx.x;
  const float* xb = xyz + (size_t)b * NPB * 3;

  float px[16], py[16], pz[16], dist[16];
  {
    const float4* gp = reinterpret_cast<const float4*>(xb + (size_t)t * 48);
    float comp[48];
#pragma unroll
    for (int v = 0; v < 12; ++v) {
      float4 r = gp[v];
      comp[v * 4 + 0] = r.x;
      comp[v * 4 + 1] = r.y;
      comp[v * 4 + 2] = r.z;
      comp[v * 4 + 3] = r.w;
    }
#pragma unroll
    for (int j = 0; j < 16; ++j) {
      px[j] = comp[3 * j + 0];
      py[j] = comp[3 * j + 1];
      pz[j] = comp[3 * j + 2];
      dist[j] = 1e10f;
    }
  }

  __shared__ __align__(16) float sD[2][8];
  __shared__ __align__(16) float4 sV[2][8];  // {x, y, z, idx_as_float}

  const int wid = t >> 6;
  const int lane = t & 63;

  // selection 0 = index 0; q broadcast via (L2-hot) global read by all lanes
  float qx = xb[0], qy = xb[1], qz = xb[2];
  if (t == 0) {
    out_idx[b * NPOINT + 0] = 0.0f;
    size_t o = (size_t)(b * NPOINT) * 3;
    out_xyz[o + 0] = qx; out_xyz[o + 1] = qy; out_xyz[o + 2] = qz;
  }

  for (int it = 1; it < NPOINT; ++it) {
    // exact per-point update + serial argmax (strict > keeps smallest j)
    float best = -1.0f;
    int bi = 0;
#pragma unroll
    for (int j = 0; j < 16; ++j) {
      float dx = __fsub_rn(px[j], qx);
      float dy = __fsub_rn(py[j], qy);
      float dz = __fsub_rn(pz[j], qz);
      float d2 = __fadd_rn(__fadd_rn(__fmul_rn(dx, dx), __fmul_rn(dy, dy)), __fmul_rn(dz, dz));
      float nd = fminf(dist[j], d2);
      dist[j] = nd;
      if (nd > best) { best = nd; bi = j; }
    }

    // wave-level f32 max (DPP; all lanes get wmax via readlane broadcast)
    const float wmax = wave_max_f32(best);
    const unsigned long long m = __ballot(best == wmax);
    const int p = it & 1;
    if (lane == (int)(__ffsll((unsigned long long)m) - 1)) {  // lowest tied lane
      sD[p][wid] = wmax;
      float sx_, sy_, sz_;
      switch (bi) {
        case 0:  sx_ = px[0];  sy_ = py[0];  sz_ = pz[0];  break;
        case 1:  sx_ = px[1];  sy_ = py[1];  sz_ = pz[1];  break;
        case 2:  sx_ = px[2];  sy_ = py[2];  sz_ = pz[2];  break;
        case 3:  sx_ = px[3];  sy_ = py[3];  sz_ = pz[3];  break;
        case 4:  sx_ = px[4];  sy_ = py[4];  sz_ = pz[4];  break;
        case 5:  sx_ = px[5];  sy_ = py[5];  sz_ = pz[5];  break;
        case 6:  sx_ = px[6];  sy_ = py[6];  sz_ = pz[6];  break;
        case 7:  sx_ = px[7];  sy_ = py[7];  sz_ = pz[7];  break;
        case 8:  sx_ = px[8];  sy_ = py[8];  sz_ = pz[8];  break;
        case 9:  sx_ = px[9];  sy_ = py[9];  sz_ = pz[9];  break;
        case 10: sx_ = px[10]; sy_ = py[10]; sz_ = pz[10]; break;
        case 11: sx_ = px[11]; sy_ = py[11]; sz_ = pz[11]; break;
        case 12: sx_ = px[12]; sy_ = py[12]; sz_ = pz[12]; break;
        case 13: sx_ = px[13]; sy_ = py[13]; sz_ = pz[13]; break;
        case 14: sx_ = px[14]; sy_ = py[14]; sz_ = pz[14]; break;
        default: sx_ = px[15]; sy_ = py[15]; sz_ = pz[15]; break;
      }
      sV[p][wid] = make_float4(sx_, sy_, sz_, (float)(t * 16 + bi));
    }
    __syncthreads();  // the only barrier per iteration
    // every thread scans the 8 wave winners (strict > => smallest wid on tie)
    const float4 d0 = *reinterpret_cast<const float4*>(&sD[p][0]);
    const float4 d1 = *reinterpret_cast<const float4*>(&sD[p][4]);
    float bd = d0.x;
    int bw = 0;
    if (d0.y > bd) { bd = d0.y; bw = 1; }
    if (d0.z > bd) { bd = d0.z; bw = 2; }
    if (d0.w > bd) { bd = d0.w; bw = 3; }
    if (d1.x > bd) { bd = d1.x; bw = 4; }
    if (d1.y > bd) { bd = d1.y; bw = 5; }
    if (d1.z > bd) { bd = d1.z; bw = 6; }
    if (d1.w > bd) { bd = d1.w; bw = 7; }
    const float4 wv = sV[p][bw];  // broadcast read (same addr all lanes)
    qx = wv.x; qy = wv.y; qz = wv.z;
    if (t == 0) {
      out_idx[b * NPOINT + it] = wv.w;
      size_t o = (size_t)(b * NPOINT + it) * 3;
      out_xyz[o + 0] = qx; out_xyz[o + 1] = qy; out_xyz[o + 2] = qz;
    }
  }
}

// ---------------------------------------------------------- feature transpose
// features f32 [64][Ntot] -> feat_t bf16 [Ntot][64]
__global__ __launch_bounds__(256) void k_transpose(const float* __restrict__ in,
                                                   unsigned short* __restrict__ out,
                                                   int Ntot) {
  __shared__ __align__(16) unsigned short tile[64][65];
  const int t = threadIdx.x;
  const int n0 = blockIdx.x * 64;
#pragma unroll
  for (int i = 0; i < 16; ++i) {
    int c = i * 4 + (t >> 6);
    int n = t & 63;
    tile[c][n] = f2bf(in[(size_t)c * Ntot + n0 + n]);
  }
  __syncthreads();
#pragma unroll
  for (int i = 0; i < 16; ++i) {
    int n = i * 4 + (t >> 6);
    int c = t & 63;
    out[(size_t)(n0 + n) * 64 + c] = tile[c][n];
  }
}

// ---------------------------------------------------------------- ball query
// One wave per center (8 waves/block). Fixed 64 rounds x 2 points/lane: no
// data-dependent loop condition, so loads pipeline across rounds. Ordered
// compaction via ballot+popcount (first-64 sub-block before second-64 keeps
// index order). Exact f32 math, strict <.
__global__ __launch_bounds__(512) void k_ball(const float* __restrict__ xyz,
                                              const float* __restrict__ fps_idx_f,
                                              float* __restrict__ sids_f) {
  __shared__ int slots[8 * NSAMPLE];
  const int b = blockIdx.x >> 6;
  const int cbase = (blockIdx.x & 63) * 8;
  const int t = threadIdx.x;
  const float* xb = xyz + (size_t)b * NPB * 3;

  const int w = t >> 6, lane = t & 63;
  const int c_local = cbase + w;
  const int ci = (int)fps_idx_f[b * NPOINT + c_local];
  const float cx = xb[ci * 3 + 0];
  const float cy = xb[ci * 3 + 1];
  const float cz = xb[ci * 3 + 2];
  const float R2 = 0.01f;  // f32(0.1*0.1), numpy weak-scalar promotion
  const unsigned long long below = (1ull << lane) - 1ull;

  int cnt = 0;
#pragma unroll 4
  for (int r = 0; r < 64; ++r) {
    const int p0 = r * 128 + lane;
    const int p1 = p0 + 64;
    float ax = xb[p0 * 3 + 0], ay = xb[p0 * 3 + 1], az = xb[p0 * 3 + 2];
    float bx = xb[p1 * 3 + 0], by = xb[p1 * 3 + 1], bz = xb[p1 * 3 + 2];
    float dxa = __fsub_rn(ax, cx), dya = __fsub_rn(ay, cy), dza = __fsub_rn(az, cz);
    float dxb = __fsub_rn(bx, cx), dyb = __fsub_rn(by, cy), dzb = __fsub_rn(bz, cz);
    float d2a = __fadd_rn(__fadd_rn(__fmul_rn(dxa, dxa), __fmul_rn(dya, dya)), __fmul_rn(dza, dza));
    float d2b = __fadd_rn(__fadd_rn(__fmul_rn(dxb, dxb), __fmul_rn(dyb, dyb)), __fmul_rn(dzb, dzb));
    const bool i0 = d2a < R2;
    const bool i1 = d2b < R2;
    const unsigned long long m0 = __ballot(i0);
    if (i0) {
      int pos = cnt + (int)__popcll(m0 & below);
      if (pos < NSAMPLE) slots[w * NSAMPLE + pos] = p0;
    }
    cnt += (int)__popcll(m0);
    const unsigned long long m1 = __ballot(i1);
    if (i1) {
      int pos = cnt + (int)__popcll(m1 & below);
      if (pos < NSAMPLE) slots[w * NSAMPLE + pos] = p1;
    }
    cnt += (int)__popcll(m1);
  }
  if (lane < NSAMPLE) {
    const int first = (cnt > 0) ? slots[w * NSAMPLE] : 0;
    const int v = (lane < cnt) ? slots[w * NSAMPLE + lane] : first;
    sids_f[((size_t)(b * NPOINT + c_local)) * NSAMPLE + lane] = (float)v;
  }
}

// ------------------------------------------------------- gather + MLP + max
// 32 lanes = 32 samples, 2 centers per wave, 8 centers per 256-thr block.
// W0/W2 f32 in LDS, W1 bf16 in LDS (~59 KB). h1/h2 in registers.
__global__ __launch_bounds__(256) void k_mlp(const float* __restrict__ xyz,
                                             const float* __restrict__ feat,
                                             const unsigned short* __restrict__ feat_t,
                                             const float* __restrict__ fps_idx_f,
                                             const float* __restrict__ sids_f,
                                             const float* __restrict__ w0g,
                                             const float* __restrict__ b0g,
                                             const float* __restrict__ w1g,
                                             const float* __restrict__ b1g,
                                             const float* __restrict__ w2g,
                                             const float* __restrict__ b2g,
                                             float* __restrict__ out_feat,
                                             int Ntot, int useT) {
  __shared__ __align__(16) float W0s[64 * 68];            // padded rows (c 67 = 0)
  __shared__ __align__(16) unsigned short W1s[64 * 64];   // bf16
  __shared__ __align__(16) float W2s[128 * 64];
  __shared__ float b0s[64], b1s[64], b2s[128];
  const int t = threadIdx.x;
  for (int i = t; i < 64 * 68; i += 256) {
    int r = i / 68, c = i - r * 68;
    W0s[i] = (c < 67) ? w0g[r * 67 + c] : 0.0f;
  }
  for (int i = t; i < 64 * 64; i += 256) W1s[i] = f2bf(w1g[i]);
  for (int i = t; i < 128 * 64; i += 256) W2s[i] = w2g[i];
  if (t < 64) b0s[t] = b0g[t];
  if (t < 64) b1s[t] = b1g[t];
  if (t < 128) b2s[t] = b2g[t];
  __syncthreads();

  const int b = blockIdx.x >> 6;
  const int c_local = (blockIdx.x & 63) * 8 + (t >> 5);
  const int s = t & 31;
  const int ci = (int)fps_idx_f[b * NPOINT + c_local];
  const float cx = xyz[((size_t)b * NPB + ci) * 3 + 0];
  const float cy = xyz[((size_t)b * NPB + ci) * 3 + 1];
  const float cz = xyz[((size_t)b * NPB + ci) * 3 + 2];
  const int id = (int)sids_f[((size_t)(b * NPOINT + c_local)) * NSAMPLE + s];

  float g[68];
  {
    const size_t pb = ((size_t)b * NPB + id) * 3;
    g[0] = __fsub_rn(xyz[pb + 0], cx);
    g[1] = __fsub_rn(xyz[pb + 1], cy);
    g[2] = __fsub_rn(xyz[pb + 2], cz);
    if (useT) {
      const uint4* fp = reinterpret_cast<const uint4*>(feat_t + ((size_t)b * NPB + id) * 64);
#pragma unroll
      for (int v = 0; v < 8; ++v) {
        uint4 r = fp[v];
        unsigned int vs[4] = {r.x, r.y, r.z, r.w};
#pragma unroll
        for (int q = 0; q < 4; ++q) {
          g[3 + v * 8 + q * 2 + 0] = __uint_as_float(vs[q] << 16);
          g[3 + v * 8 + q * 2 + 1] = __uint_as_float(vs[q] & 0xFFFF0000u);
        }
      }
    } else {
      const float* col = feat + (size_t)(b * NPB + id);
#pragma unroll 8
      for (int c = 0; c < 64; ++c) g[3 + c] = col[(size_t)c * Ntot];
    }
    g[67] = 0.0f;
  }

  float h1[64];
#pragma unroll
  for (int o = 0; o < 64; ++o) {
    float acc = b0s[o];
    const float4* wp = reinterpret_cast<const float4*>(&W0s[o * 68]);
#pragma unroll
    for (int c4 = 0; c4 < 17; ++c4) {
      float4 wv = wp[c4];
      acc += wv.x * g[c4 * 4 + 0];
      acc += wv.y * g[c4 * 4 + 1];
      acc += wv.z * g[c4 * 4 + 2];
      acc += wv.w * g[c4 * 4 + 3];
    }
    h1[o] = fmaxf(acc, 0.0f);
  }
  float h2[64];
#pragma unroll
  for (int o = 0; o < 64; ++o) {
    float acc = b1s[o];
    const uint2* wp = reinterpret_cast<const uint2*>(&W1s[o * 64]);
#pragma unroll
    for (int c4 = 0; c4 < 16; ++c4) {
      uint2 u = wp[c4];
      acc += __uint_as_float(u.x << 16) * h1[c4 * 4 + 0];
      acc += __uint_as_float(u.x & 0xFFFF0000u) * h1[c4 * 4 + 1];
      acc += __uint_as_float(u.y << 16) * h1[c4 * 4 + 2];
      acc += __uint_as_float(u.y & 0xFFFF0000u) * h1[c4 * 4 + 3];
    }
    h2[o] = fmaxf(acc, 0.0f);
  }
#pragma unroll 1
  for (int o = 0; o < 128; ++o) {
    float acc = b2s[o];
    const float4* wp = reinterpret_cast<const float4*>(&W2s[o * 64]);
#pragma unroll
    for (int c4 = 0; c4 < 16; ++c4) {
      float4 wv = wp[c4];
      acc += wv.x * h2[c4 * 4 + 0];
      acc += wv.y * h2[c4 * 4 + 1];
      acc += wv.z * h2[c4 * 4 + 2];
      acc += wv.w * h2[c4 * 4 + 3];
    }
    float v = fmaxf(acc, 0.0f);
#pragma unroll
    for (int off = 16; off >= 1; off >>= 1) v = fmaxf(v, __shfl_xor(v, off));
    if (s == 0) out_feat[((size_t)b * 128 + o) * NPOINT + c_local] = v;
  }
}

// ------------------------------------------------------------------- launch
extern "C" void kernel_launch(void* const* d_in, const int* in_sizes, int n_in,
                              void* d_out, int out_size, void* d_ws, size_t ws_size,
                              hipStream_t stream) {
  (void)n_in; (void)out_size;
  const float* xyz = (const float*)d_in[0];
  const float* feat = (const float*)d_in[1];
  // d_in[2] = num_points (8192, fixed by setup)
  const float* w0 = (const float*)d_in[3];
  const float* b0 = (const float*)d_in[4];
  const float* w1 = (const float*)d_in[5];
  const float* b1 = (const float*)d_in[6];
  const float* w2 = (const float*)d_in[7];
  const float* b2 = (const float*)d_in[8];

  const int Ntot = in_sizes[0] / 3;   // 65536
  const int B = Ntot / NPB;           // 8

  float* out = (float*)d_out;
  float* o_xyz = out;                                    // [B,512,3]
  float* o_idx = o_xyz + (size_t)B * NPOINT * 3;         // [B,512]
  float* o_feat = o_idx + (size_t)B * NPOINT;            // [B,128,512]
  float* o_sids = o_feat + (size_t)B * 128 * NPOINT;     // [B,512,32]

  // Workspace: only the transposed-features buffer (bf16), only if it fits.
  const size_t ft_bytes = (size_t)Ntot * 64 * 2;         // 8 MB
  const int useT = (ws_size >= ft_bytes) ? 1 : 0;
  unsigned short* ft_ws = (unsigned short*)d_ws;

  if (useT) {
    k_transpose<<<dim3(Ntot / 64), dim3(256), 0, stream>>>(feat, ft_ws, Ntot);
  }
  k_fps<<<dim3(B), dim3(512), 0, stream>>>(xyz, o_xyz, o_idx);
  k_ball<<<dim3(B * 64), dim3(512), 0, stream>>>(xyz, o_idx, o_sids);
  k_mlp<<<dim3(B * 64), dim3(256), 0, stream>>>(xyz, feat, ft_ws, o_idx, o_sids,
                                                w0, b0, w1, b1, w2, b2, o_feat,
                                                Ntot, useT);
}